// Round 7
// baseline (452.492 us; speedup 1.0000x reference)
//
#include <hip/hip_runtime.h>
#include <stdint.h>

// Problem constants (DGCNN propagation). Inputs/outputs are FLOAT32 (per the
// reference's jnp.float32 setup_inputs); internals use bf16 MFMA (2% threshold).
#define B_   16
#define CIN  384     // C
#define GS   4096    // source points (power of 2 -> maskable)
#define GD   1024    // query points  (power of 2 -> maskable)
#define M1   512     // block1 out channels
#define K2C  512     // block2 in channels (= M1)
#define M2   384     // block2 out channels (= C)
#define ROWS2 768    // stacked block2 GEMM rows (W2a on top of W2d)
#define NEG  0.2f
#define EPS_ 1e-5f

typedef __bf16 bf16x8 __attribute__((ext_vector_type(8)));
typedef float  f32x4  __attribute__((ext_vector_type(4)));
typedef float  f32x2  __attribute__((ext_vector_type(2)));
typedef unsigned long long u64k;

__device__ __forceinline__ float bf2f(ushort u) {
  uint32_t v = ((uint32_t)u) << 16;
  return __builtin_bit_cast(float, v);
}
__device__ __forceinline__ ushort f2bf(float f) {
  uint32_t x = __builtin_bit_cast(uint32_t, f);
  x += 0x7FFFu + ((x >> 16) & 1u);
  return (ushort)(x >> 16);
}

// Packed dual-f32 ops (CDNA full-rate packed fp32). Each half is an ordinary
// IEEE f32 op -> bit-identical to scalar mul/add in the same order.
__device__ __forceinline__ f32x2 pk_mul(f32x2 a, f32x2 b) {
  f32x2 d; asm("v_pk_mul_f32 %0, %1, %2" : "=v"(d) : "v"(a), "v"(b)); return d;
}
__device__ __forceinline__ f32x2 pk_add(f32x2 a, f32x2 b) {
  f32x2 d; asm("v_pk_add_f32 %0, %1, %2" : "=v"(d) : "v"(a), "v"(b)); return d;
}
__device__ __forceinline__ f32x2 pk_fma(f32x2 a, f32x2 b, f32x2 c) {
  f32x2 d; asm("v_pk_fma_f32 %0, %1, %2, %3" : "=v"(d) : "v"(a), "v"(b), "v"(c)); return d;
}

// async global->LDS, 16B per lane. Dest must be wave-uniform base; HW adds lane*16.
__device__ __forceinline__ void gload16(const void* g, void* l) {
  __builtin_amdgcn_global_load_lds(
      (const __attribute__((address_space(1))) void*)g,
      (__attribute__((address_space(3))) void*)l, 16, 0, 0);
}

// ---------------- transpose+convert [b][C][N] f32 -> [b][N][C] bf16 ----------------
__global__ void k_transpose(const float* __restrict__ src, ushort* __restrict__ dst,
                            int Cdim, int N) {
  __shared__ ushort tile[32][33];
  int b = blockIdx.z;
  int n0 = blockIdx.x * 32, c0 = blockIdx.y * 32;
  const float* s = src + (size_t)b * Cdim * N;
  ushort* d = dst + (size_t)b * Cdim * N;
  int tx = threadIdx.x, ty = threadIdx.y;
#pragma unroll
  for (int i = 0; i < 4; i++) {
    int c = c0 + ty + i * 8;
    tile[ty + i * 8][tx] = f2bf(s[(size_t)c * N + n0 + tx]);
  }
  __syncthreads();
#pragma unroll
  for (int i = 0; i < 4; i++) {
    int n = n0 + ty + i * 8;
    d[(size_t)n * Cdim + c0 + tx] = tile[tx][ty + i * 8];
  }
}

// ---------------- weight prep (both layers, one launch) ----------------
// Wa = bf16(W[:, :Kh]), Wd = bf16(W[:, Kh:] - W[:, :Kh])
// blocks 0..767: W1 (Kh=384, 512*384 elems); blocks 768..1535: W2 (Kh=512, 384*512 elems)
__global__ void k_wprep2(const float* __restrict__ W1, const float* __restrict__ W2,
                         ushort* __restrict__ W1a, ushort* __restrict__ W1d,
                         ushort* __restrict__ W2a, ushort* __restrict__ W2d) {
  int blk = blockIdx.x;
  if (blk < 768) {
    int t = blk * 256 + threadIdx.x;
    int o = t / 384, c = t % 384;
    float wa = W1[(size_t)o * 768 + c];
    float wb = W1[(size_t)o * 768 + 384 + c];
    W1a[t] = f2bf(wa);
    W1d[t] = f2bf(wb - wa);
  } else {
    int t = (blk - 768) * 256 + threadIdx.x;
    int o = t / 512, c = t % 512;
    float wa = W2[(size_t)o * 1024 + c];
    float wb = W2[(size_t)o * 1024 + 512 + c];
    W2a[t] = f2bf(wa);
    W2d[t] = f2bf(wb - wa);
  }
}

// ---------------- s2 prep (both coord sets, one launch) ----------------
// s2[b][j] = (x*x + y*y) + z*z, identical op order to the verified serial version.
__global__ void k_s2both(const float* __restrict__ cs, const float* __restrict__ cq,
                         float* __restrict__ s2s, float* __restrict__ s2q) {
#pragma clang fp contract(off)
  int b = blockIdx.z;
  int i = blockIdx.x * 256 + threadIdx.x;
  if (i < GS) {
    const float* cb = cs + (size_t)b * 3 * GS;
    float x = cb[i], y = cb[GS + i], z = cb[2 * GS + i];
    s2s[(size_t)b * GS + i] = (x * x + y * y) + z * z;
  } else {
    int j = i - GS;
    const float* cb = cq + (size_t)b * 3 * GD;
    float x = cb[j], y = cb[GD + j], z = cb[2 * GD + j];
    s2q[(size_t)b * GD + j] = (x * x + y * y) + z * z;
  }
}

// ---------------- kNN: wave-per-2-queries, u64-key sort4+bitonic-merge top-4 ----------------
// Distance values bit-identical to the verified serial version (see r1/r3 notes):
// s2 precomputed, dot via pk ops, d = pk_fma(dot,-2,q2+s2) == (q2+s2)-2*dot exactly.
// Selection: key = (monotone d bits, j) as u64 -> lex (d, idx) order == jax top_k
// tie-break (d never -0.0: q2+s2 >= 0, exact-zero fma -> +0.0 in RNE).
// Each wave processes TWO queries against the same candidate stream: the 4
// float4 loads per iteration are shared (halved load issue per query-candidate)
// and the two independent sort/merge chains double ILP to hide VALU latency.
// Loads double-buffered (2-deep unroll, no register copies).
__device__ __forceinline__ uint32_t dmap(float d) {
  uint32_t u = __builtin_bit_cast(uint32_t, d);
  return u ^ (((uint32_t)((int32_t)u >> 31)) | 0x80000000u);  // monotone map f32 -> u32
}
__device__ __forceinline__ u64k mkkey(uint32_t hi, uint32_t lo) {
  uint2 t; t.x = lo; t.y = hi;               // register-pair build: no shift/or
  return __builtin_bit_cast(u64k, t);
}
__device__ __forceinline__ void kce(u64k& a, u64k& b) {
  bool c = b < a;
  u64k lo = c ? b : a, hi = c ? a : b;
  a = lo; b = hi;
}
__device__ __forceinline__ void klmin(u64k& a, u64k b) { a = b < a ? b : a; }

template<int GSRC>
__global__ __launch_bounds__(256) void k_knn(const float* __restrict__ cq,
                                             const float* __restrict__ ck,
                                             const float* __restrict__ s2qry,
                                             const float* __restrict__ s2src,
                                             int* __restrict__ idx) {
  constexpr int ITERS = GSRC / 256;
  static_assert(ITERS % 2 == 0, "even iteration count required for 2-deep unroll");
  int tid = threadIdx.x;
  int lane = tid & 63, wv = tid >> 6;
  int b = blockIdx.y;
  int qA = blockIdx.x * 8 + wv * 2;     // two queries per wave
  int qB = qA + 1;
  const float* cqb = cq + (size_t)b * 3 * GD;
  const float* ckb = ck + (size_t)b * 3 * GSRC;
  const float* s2b = s2src + (size_t)b * GSRC;
  float qxA = cqb[qA], qyA = cqb[GD + qA], qzA = cqb[2 * GD + qA];
  float qxB = cqb[qB], qyB = cqb[GD + qB], qzB = cqb[2 * GD + qB];
  float q2A = s2qry[(size_t)b * GD + qA];
  float q2B = s2qry[(size_t)b * GD + qB];
  f32x2 qxpA = {qxA, qxA}, qypA = {qyA, qyA}, qzpA = {qzA, qzA}, q2pA = {q2A, q2A};
  f32x2 qxpB = {qxB, qxB}, qypB = {qyB, qyB}, qzpB = {qzB, qzB}, q2pB = {q2B, q2B};
  f32x2 m2p = {-2.f, -2.f};

  u64k kA0 = ~0ull, kA1 = ~0ull, kA2 = ~0ull, kA3 = ~0ull;  // sorted-4 asc (query A)
  u64k kB0 = ~0ull, kB1 = ~0ull, kB2 = ~0ull, kB3 = ~0ull;  // sorted-4 asc (query B)

#define KNN_Q(QXP, QYP, QZP, Q2P, K0, K1, K2, K3)                              \
  {                                                                            \
    f32x2 dotl = pk_add(pk_add(pk_mul(QXP, xl), pk_mul(QYP, yl)), pk_mul(QZP, zl)); \
    f32x2 doth = pk_add(pk_add(pk_mul(QXP, xh), pk_mul(QYP, yh)), pk_mul(QZP, zh)); \
    f32x2 dl = pk_fma(dotl, m2p, pk_add(Q2P, sl));                             \
    f32x2 dh = pk_fma(doth, m2p, pk_add(Q2P, sh));                             \
    u64k n0 = mkkey(dmap(dl.x), j0u);                                          \
    u64k n1 = mkkey(dmap(dl.y), j0u + 1);                                      \
    u64k n2 = mkkey(dmap(dh.x), j0u + 2);                                      \
    u64k n3 = mkkey(dmap(dh.y), j0u + 3);                                      \
    kce(n0, n1); kce(n2, n3); kce(n0, n2); kce(n1, n3); kce(n1, n2);           \
    klmin(K0, n3); klmin(K1, n2); klmin(K2, n1); klmin(K3, n0);                \
    kce(K0, K2); kce(K1, K3); kce(K0, K1); kce(K2, K3);                        \
  }

#define KNN_STEP(Xv, Yv, Zv, Sv, J0)                                           \
  {                                                                            \
    f32x2 xl = {Xv.x, Xv.y}, xh = {Xv.z, Xv.w};                                \
    f32x2 yl = {Yv.x, Yv.y}, yh = {Yv.z, Yv.w};                                \
    f32x2 zl = {Zv.x, Zv.y}, zh = {Zv.z, Zv.w};                                \
    f32x2 sl = {Sv.x, Sv.y}, sh = {Sv.z, Sv.w};                                \
    uint32_t j0u = (uint32_t)(J0);                                             \
    KNN_Q(qxpA, qypA, qzpA, q2pA, kA0, kA1, kA2, kA3);                         \
    KNN_Q(qxpB, qypB, qzpB, q2pB, kB0, kB1, kB2, kB3);                         \
  }

#define KNN_LOAD(Xv, Yv, Zv, Sv, J)                                            \
  {                                                                            \
    Xv = *reinterpret_cast<const float4*>(ckb + (J));                          \
    Yv = *reinterpret_cast<const float4*>(ckb + GSRC + (J));                   \
    Zv = *reinterpret_cast<const float4*>(ckb + 2 * GSRC + (J));               \
    Sv = *reinterpret_cast<const float4*>(s2b + (J));                          \
  }

  int base = lane * 4;
  float4 X0, Y0, Z0, S0, X1, Y1, Z1, S1;
  KNN_LOAD(X0, Y0, Z0, S0, base);
  for (int it = 0; it < ITERS; it += 2) {
    int j0 = it * 256 + base;
    KNN_LOAD(X1, Y1, Z1, S1, j0 + 256);           // prefetch it+1 (always valid)
    KNN_STEP(X0, Y0, Z0, S0, j0);
    if (it + 2 < ITERS) KNN_LOAD(X0, Y0, Z0, S0, j0 + 512);  // prefetch it+2
    KNN_STEP(X1, Y1, Z1, S1, j0 + 256);
  }
#undef KNN_STEP
#undef KNN_Q
#undef KNN_LOAD

  // 6-step butterfly: merge two sorted 4-lists -> lowest 4 (bitonic, lex order),
  // run independently for both queries.
#pragma unroll
  for (int off = 1; off < 64; off <<= 1) {
    u64k p0 = __shfl_xor(kA0, off), p1 = __shfl_xor(kA1, off);
    u64k p2 = __shfl_xor(kA2, off), p3 = __shfl_xor(kA3, off);
    klmin(kA0, p3); klmin(kA1, p2); klmin(kA2, p1); klmin(kA3, p0);
    kce(kA0, kA2); kce(kA1, kA3); kce(kA0, kA1); kce(kA2, kA3);
    u64k r0 = __shfl_xor(kB0, off), r1 = __shfl_xor(kB1, off);
    u64k r2 = __shfl_xor(kB2, off), r3 = __shfl_xor(kB3, off);
    klmin(kB0, r3); klmin(kB1, r2); klmin(kB2, r1); klmin(kB3, r0);
    kce(kB0, kB2); kce(kB1, kB3); kce(kB0, kB1); kce(kB2, kB3);
  }
  if (lane == 0) {
    int4 ra;
    ra.x = (int)(uint32_t)kA0; ra.y = (int)(uint32_t)kA1;
    ra.z = (int)(uint32_t)kA2; ra.w = (int)(uint32_t)kA3;
    *reinterpret_cast<int4*>(&idx[((size_t)b * GD + qA) * 4]) = ra;
    int4 rb;
    rb.x = (int)(uint32_t)kB0; rb.y = (int)(uint32_t)kB1;
    rb.z = (int)(uint32_t)kB2; rb.w = (int)(uint32_t)kB3;
    *reinterpret_cast<int4*>(&idx[((size_t)b * GD + qB) * 4]) = rb;
  }
}

// ---------------- bf16 MFMA GEMM (m97 structure): out[b] = W(MxK) * Xt[b](NxK)^T ----------------
// 128x128 tile, BK=32, 256 threads = 4 waves, each wave 64x64 via 4x4 mfma_f32_16x16x32_bf16.
// Staging via global_load_lds width-16 into LINEAR [128][32] LDS (dest = wave-uniform
// base + lane*16; thread t's (row=t>>2, col16=(t&3)) maps to LDS byte t*16 exactly).
template<bool OUT_BF16>
__global__ __launch_bounds__(256) void k_gemm(const ushort* __restrict__ W,
                                              const ushort* __restrict__ Xt,
                                              void* __restrict__ outv,
                                              int M, int Kd, int N) {
  __shared__ __align__(16) ushort As[128 * 32];  // 8 KB, linear
  __shared__ __align__(16) ushort Bs[128 * 32];  // 8 KB, linear
  int b = blockIdx.z;
  const ushort* X = Xt + (size_t)b * N * Kd;
  int m0 = blockIdx.y * 128, n0 = blockIdx.x * 128;
  int tid = threadIdx.x;
  int w = tid >> 6, lane = tid & 63;
  int lr = lane & 15, lq = lane >> 4;
  int mw = (w >> 1) * 64, nw = (w & 1) * 64;
  int r0 = tid >> 2, c0 = tid & 3;

  // wave-uniform LDS dest bases (ushort units): first half rows at w*512, second at 2048+w*512
  ushort* dA0 = As + w * 512;
  ushort* dA1 = As + 2048 + w * 512;
  ushort* dB0 = Bs + w * 512;
  ushort* dB1 = Bs + 2048 + w * 512;
  const ushort* gA0 = W + (size_t)(m0 + r0) * Kd + c0 * 8;
  const ushort* gA1 = W + (size_t)(m0 + r0 + 64) * Kd + c0 * 8;
  const ushort* gB0 = X + (size_t)(n0 + r0) * Kd + c0 * 8;
  const ushort* gB1 = X + (size_t)(n0 + r0 + 64) * Kd + c0 * 8;

  f32x4 zero = {0.f, 0.f, 0.f, 0.f};
  f32x4 acc[4][4];
#pragma unroll
  for (int mi = 0; mi < 4; mi++)
#pragma unroll
    for (int ni = 0; ni < 4; ni++) acc[mi][ni] = zero;

  int nk = Kd / 32;
  for (int kt = 0; kt < nk; kt++) {
    int kk = kt * 32;
    __syncthreads();                    // prev-iter LDS reads done
    gload16(gA0 + kk, dA0);
    gload16(gA1 + kk, dA1);
    gload16(gB0 + kk, dB0);
    gload16(gB1 + kk, dB1);
    __syncthreads();                    // drains vmcnt before barrier (compiler)
    bf16x8 af[4], bfr[4];
#pragma unroll
    for (int mi = 0; mi < 4; mi++)
      af[mi] = *reinterpret_cast<const bf16x8*>(&As[(mw + mi * 16 + lr) * 32 + lq * 8]);
#pragma unroll
    for (int ni = 0; ni < 4; ni++)
      bfr[ni] = *reinterpret_cast<const bf16x8*>(&Bs[(nw + ni * 16 + lr) * 32 + lq * 8]);
#pragma unroll
    for (int mi = 0; mi < 4; mi++)
#pragma unroll
      for (int ni = 0; ni < 4; ni++)
        acc[mi][ni] = __builtin_amdgcn_mfma_f32_16x16x32_bf16(af[mi], bfr[ni], acc[mi][ni], 0, 0, 0);
  }
#pragma unroll
  for (int mi = 0; mi < 4; mi++) {
    int m = m0 + mw + mi * 16 + lq * 4;
#pragma unroll
    for (int ni = 0; ni < 4; ni++) {
      int n = n0 + nw + ni * 16 + lr;
#pragma unroll
      for (int r = 0; r < 4; r++) {
        size_t off = (size_t)b * M * N + (size_t)(m + r) * N + n;
        if constexpr (OUT_BF16) ((ushort*)outv)[off] = f2bf(acc[mi][ni][r]);
        else                    ((float*)outv)[off] = acc[mi][ni][r];
      }
    }
  }
}

// ---------------- GN1 stats + Ysel pass: y = bf16(A)[gather] + Bq ----------------
// Per (o,g): accumulate sum/ssq AND write Ysel[o][g] = (gamma[o]>=0 ? max_k y : min_k y).
// Monotonicity of t(y)=leaky((y-mean)*rstd*ga+be) in y (rstd>0) makes
// max_k t(y_k) == t(Ysel) exactly (weakly-monotone rounded op chain).
// A-row (8KB) and idx table (16KB) staged in LDS: coalesced global reads only.
__global__ __launch_bounds__(256) void k_stats1y(const ushort* __restrict__ A,
                                                 const float* __restrict__ Bq,
                                                 const int* __restrict__ idx1,
                                                 const float* __restrict__ gam,
                                                 float* __restrict__ Ysel,
                                                 float* __restrict__ part) {
  __shared__ __align__(16) ushort Arow[GS];   // 8 KB
  __shared__ __align__(16) int ids[GD * 4];   // 16 KB
  __shared__ float rs[256], rq[256];
  int s = blockIdx.x, grp = blockIdx.y, b = blockIdx.z;
  int tid = threadIdx.x;
  for (int i = tid; i < GD; i += 256) {
    int4 v = *reinterpret_cast<const int4*>(&idx1[((size_t)b * GD + i) * 4]);
    v.x &= (GS - 1); v.y &= (GS - 1); v.z &= (GS - 1); v.w &= (GS - 1);
    *reinterpret_cast<int4*>(&ids[i * 4]) = v;
  }
  float sum = 0.f, ssq = 0.f;
  for (int oi = 0; oi < 16; oi++) {
    int o = grp * 128 + s * 16 + oi;
    const ushort* Ar = A + ((size_t)b * M1 + o) * GS;
    __syncthreads();  // prev-iter gathers done (also covers ids staging on oi=0)
#pragma unroll
    for (int i = tid * 8; i < GS; i += 2048)
      *reinterpret_cast<uint4*>(&Arow[i]) = *reinterpret_cast<const uint4*>(&Ar[i]);
    __syncthreads();
    const float* Br = Bq + ((size_t)b * M1 + o) * GD;
    float* Yr = Ysel + ((size_t)b * M1 + o) * GD;
    float sgn = gam[o];
    for (int g = tid; g < GD; g += 256) {
      int4 id = *reinterpret_cast<const int4*>(&ids[g * 4]);
      float base = Br[g];
      float y0 = bf2f(Arow[id.x]) + base;
      float y1 = bf2f(Arow[id.y]) + base;
      float y2 = bf2f(Arow[id.z]) + base;
      float y3 = bf2f(Arow[id.w]) + base;
      sum += y0 + y1 + y2 + y3;
      ssq += y0 * y0 + y1 * y1 + y2 * y2 + y3 * y3;
      float mx = fmaxf(fmaxf(y0, y1), fmaxf(y2, y3));
      float mn = fminf(fminf(y0, y1), fminf(y2, y3));
      Yr[g] = (sgn >= 0.f) ? mx : mn;
    }
  }
  rs[tid] = sum; rq[tid] = ssq;
  __syncthreads();
  for (int t = 128; t > 0; t >>= 1) {
    if (tid < t) { rs[tid] += rs[tid + t]; rq[tid] += rq[tid + t]; }
    __syncthreads();
  }
  if (tid == 0) {
    int key = ((b * 4 + grp) * 8 + s) * 2;
    part[key] = rs[0]; part[key + 1] = rq[0];
  }
}

// ---------------- GN2 stats + Ysel pass (stacked Y2 layout [b][768][1024]) ----------------
// rows 0..383 = A2 (W2a*hT), rows 384..767 = B2q (W2d*hT). 96-ch groups, 12 ch/split.
__global__ __launch_bounds__(256) void k_stats2y(const float* __restrict__ Y2,
                                                 const int* __restrict__ idx2,
                                                 const float* __restrict__ gam,
                                                 float* __restrict__ Ysel,
                                                 float* __restrict__ part) {
  __shared__ __align__(16) float Arow[GD];    // 4 KB
  __shared__ __align__(16) int ids[GD * 4];   // 16 KB
  __shared__ float rs[256], rq[256];
  int s = blockIdx.x, grp = blockIdx.y, b = blockIdx.z;
  int tid = threadIdx.x;
  for (int i = tid; i < GD; i += 256) {
    int4 v = *reinterpret_cast<const int4*>(&idx2[((size_t)b * GD + i) * 4]);
    v.x &= (GD - 1); v.y &= (GD - 1); v.z &= (GD - 1); v.w &= (GD - 1);
    *reinterpret_cast<int4*>(&ids[i * 4]) = v;
  }
  float sum = 0.f, ssq = 0.f;
  for (int oi = 0; oi < 12; oi++) {
    int o = grp * 96 + s * 12 + oi;
    const float* Ar = Y2 + ((size_t)b * ROWS2 + o) * GD;
    __syncthreads();
#pragma unroll
    for (int i = tid * 4; i < GD; i += 1024)
      *reinterpret_cast<float4*>(&Arow[i]) = *reinterpret_cast<const float4*>(&Ar[i]);
    __syncthreads();
    const float* Br = Y2 + ((size_t)b * ROWS2 + 384 + o) * GD;
    float* Yr = Ysel + ((size_t)b * M2 + o) * GD;
    float sgn = gam[o];
    for (int g = tid; g < GD; g += 256) {
      int4 id = *reinterpret_cast<const int4*>(&ids[g * 4]);
      float base = Br[g];
      float y0 = Arow[id.x] + base;
      float y1 = Arow[id.y] + base;
      float y2 = Arow[id.z] + base;
      float y3 = Arow[id.w] + base;
      sum += y0 + y1 + y2 + y3;
      ssq += y0 * y0 + y1 * y1 + y2 * y2 + y3 * y3;
      float mx = fmaxf(fmaxf(y0, y1), fmaxf(y2, y3));
      float mn = fminf(fminf(y0, y1), fminf(y2, y3));
      Yr[g] = (sgn >= 0.f) ? mx : mn;
    }
  }
  rs[tid] = sum; rq[tid] = ssq;
  __syncthreads();
  for (int t = 128; t > 0; t >>= 1) {
    if (tid < t) { rs[tid] += rs[tid + t]; rq[tid] += rq[tid + t]; }
    __syncthreads();
  }
  if (tid == 0) {
    int key = ((b * 4 + grp) * 8 + s) * 2;
    part[key] = rs[0]; part[key + 1] = rq[0];
  }
}

// ---------------- h = leaky(GN(Ysel)); statsfin inlined (identical arith order) ----------------
// No gathers: Ysel already holds the k-max (or k-min for gamma<0) of y.
// Each block spans o0..o0+63, all within one 128-ch group -> one (mean, rstd).
__global__ void k_h2(const float* __restrict__ Ysel, const float* __restrict__ part,
                     const float* __restrict__ gam, const float* __restrict__ bet,
                     ushort* __restrict__ hT) {
  __shared__ ushort tile[64][66];  // pitch 66: conflict-free column reads
  int g0 = blockIdx.x * 64, o0 = blockIdx.y * 64, b = blockIdx.z;
  int tid = threadIdx.x;
  int tkey = b * 4 + (o0 >> 7);
  float s = 0.f, q = 0.f;
#pragma unroll
  for (int i = 0; i < 8; i++) { s += part[(tkey * 8 + i) * 2]; q += part[(tkey * 8 + i) * 2 + 1]; }
  float mean = s * (1.0f / 524288.0f);
  float var = q * (1.0f / 524288.0f) - mean * mean;
  float rstd = 1.0f / sqrtf(fmaxf(var, 0.0f) + EPS_);
  int gx = tid & 63, oy = tid >> 6;
#pragma unroll
  for (int oi = 0; oi < 16; oi++) {
    int ol = oi * 4 + oy;
    int o = o0 + ol;
    float y = Ysel[((size_t)b * M1 + o) * GD + g0 + gx];
    float v = (y - mean) * rstd * gam[o] + bet[o];
    v = v >= 0.f ? v : NEG * v;
    tile[ol][gx] = f2bf(v);
  }
  __syncthreads();
  int col = tid & 63, r4 = tid >> 6;
#pragma unroll
  for (int i = 0; i < 16; i++) {
    int gl = i * 4 + r4;
    hT[((size_t)b * GD + g0 + gl) * K2C + o0 + col] = tile[col][gl];
  }
}

// ---------------- final: out = leaky(GN2(Ysel2)), statsfin inlined -> f32 ----------------
__global__ void k_out2(const float* __restrict__ Ysel2, const float* __restrict__ part,
                       const float* __restrict__ gam, const float* __restrict__ bet,
                       float* __restrict__ out) {
  int b = blockIdx.z, o = blockIdx.y;
  int g = blockIdx.x * 256 + threadIdx.x;
  int tkey = b * 4 + o / 96;
  float s = 0.f, q = 0.f;
#pragma unroll
  for (int i = 0; i < 8; i++) { s += part[(tkey * 8 + i) * 2]; q += part[(tkey * 8 + i) * 2 + 1]; }
  float mean = s * (1.0f / 393216.0f);
  float var = q * (1.0f / 393216.0f) - mean * mean;
  float rstd = 1.0f / sqrtf(fmaxf(var, 0.0f) + EPS_);
  float y = Ysel2[((size_t)b * M2 + o) * GD + g];
  float v = (y - mean) * rstd * gam[o] + bet[o];
  v = v >= 0.f ? v : NEG * v;
  out[((size_t)b * M2 + o) * GD + g] = v;
}

extern "C" void kernel_launch(void* const* d_in, const int* in_sizes, int n_in,
                              void* d_out, int out_size, void* d_ws, size_t ws_size,
                              hipStream_t stream) {
  (void)in_sizes; (void)n_in; (void)out_size;
  const float* coor  = (const float*)d_in[0];  // [16][3][4096] f32
  const float* f     = (const float*)d_in[1];  // [16][384][4096]
  const float* coorq = (const float*)d_in[2];  // [16][3][1024]
  const float* fq    = (const float*)d_in[3];  // [16][384][1024]
  const float* W1    = (const float*)d_in[4];  // [512][768]
  const float* g1    = (const float*)d_in[5];
  const float* b1    = (const float*)d_in[6];
  const float* W2    = (const float*)d_in[7];  // [384][1024]
  const float* g2    = (const float*)d_in[8];
  const float* b2    = (const float*)d_in[9];

  // Required workspace ~182.5 MB (internal buffers unchanged; skip cleanly if short).
  if (ws_size < 182468608u) return;

  char* ws = (char*)d_ws;
  int*    idx1 = (int*)(ws + 0);            // 256 KB
  int*    idx2 = (int*)(ws + 0x40000);      // 256 KB
  float*  s1p  = (float*)(ws + 0x80000);    // 4 KB
  float*  s2p  = (float*)(ws + 0x82000);
  ushort* W1a  = (ushort*)(ws + 0x84000);           // 512*384 bf16
  ushort* W1d  = W1a + (size_t)512 * 384;
  ushort* W2a  = W1d + (size_t)512 * 384;           // 384*512 (W2d contiguous after -> stacked M=768 GEMM)
  ushort* W2d  = W2a + (size_t)384 * 512;
  ushort* fT   = W2d + (size_t)384 * 512;           // [16][4096][384] bf16, 50.33 MB
  ushort* fqT  = fT + (size_t)B_ * GS * CIN;        // [16][1024][384] bf16, 12.6 MB
  ushort* Abuf = fqT + (size_t)B_ * GD * CIN;       // [16][512][4096] bf16, 67.1 MB
  float*  Bq   = (float*)(Abuf + (size_t)B_ * M1 * GS);   // [16][512][1024] f32, 33.6 MB
  ushort* hT   = (ushort*)((char*)Bq + (size_t)B_ * M1 * GD * 4); // [16][1024][512] bf16, 16.8 MB
  // Y2 = stacked block2 GEMM output [16][768][1024] f32 (rows 0..383 = A2, 384..767 = B2q),
  // 50.3 MB, aliases dead fT (Ysel1 consumed by k_h2 before the stacked GEMM writes here).
  float*  Y2   = (float*)fT;
  // Ysel1 aliases dead fT (consumed by k_h2 BEFORE the stacked GEMM overwrites).
  float*  Ysel1 = (float*)fT;                       // [16][512][1024] f32, 33.6 MB
  // Ysel2 aliases dead Abuf (Abuf's last reader is k_stats1y).
  float*  Ysel2 = (float*)Abuf;                     // [16][384][1024] f32, 25.2 MB
  // s2 tables live in the not-yet-written hT region (read only by k_knn, which
  // completes before k_h2 writes hT -> stream-ordered safe; no extra ws needed).
  float*  s2s  = (float*)hT;                        // [16][4096] f32, 256 KB
  float*  s2q  = s2s + (size_t)B_ * GS;             // [16][1024] f32, 64 KB

  // 1. transposes (+f32->bf16 convert) + fused weight prep + fused s2 tables
  k_transpose<<<dim3(GS / 32, CIN / 32, B_), dim3(32, 8), 0, stream>>>(f, fT, CIN, GS);
  k_transpose<<<dim3(GD / 32, CIN / 32, B_), dim3(32, 8), 0, stream>>>(fq, fqT, CIN, GD);
  k_wprep2<<<dim3(1536), 256, 0, stream>>>(W1, W2, W1a, W1d, W2a, W2d);
  k_s2both<<<dim3((GS + GD) / 256, 1, B_), 256, 0, stream>>>(coor, coorq, s2s, s2q);

  // 2. kNN index sets (2 queries/wave, shared candidate loads, double-buffered)
  k_knn<GS><<<dim3(GD / 8, B_), 256, 0, stream>>>(coorq, coor, s2q, s2s, idx1);
  k_knn<GD><<<dim3(GD / 8, B_), 256, 0, stream>>>(coorq, coorq, s2q, s2q, idx2);

  // 3. block1 GEMMs: A = W1a*f (bf16 out), Bq = W1d*fq (f32 out)
  k_gemm<true ><<<dim3(GS / 128, M1 / 128, B_), 256, 0, stream>>>(W1a, fT, Abuf, M1, CIN, GS);
  k_gemm<false><<<dim3(GD / 128, M1 / 128, B_), 256, 0, stream>>>(W1d, fqT, Bq, M1, CIN, GD);

  // 4. GN1 stats + Ysel1 (single gather pass), then streaming h transform (statsfin inline)
  k_stats1y<<<dim3(8, 4, B_), 256, 0, stream>>>(Abuf, Bq, idx1, g1, Ysel1, s1p);
  k_h2<<<dim3(GD / 64, M1 / 64, B_), 256, 0, stream>>>(Ysel1, s1p, g1, b1, hT);

  // 5. block2 GEMM, stacked: [W2a; W2d] (M=768) * hT -> Y2 (one pass over hT)
  k_gemm<false><<<dim3(GD / 128, ROWS2 / 128, B_), 256, 0, stream>>>(W2a, hT, Y2, ROWS2, K2C, GD);

  // 6. GN2 stats + Ysel2 (single gather pass), then streaming final output (statsfin inline)
  k_stats2y<<<dim3(8, 4, B_), 256, 0, stream>>>(Y2, idx2, g2, Ysel2, s2p);
  k_out2<<<dim3(GD / 256, M2, B_), 256, 0, stream>>>(Ysel2, s2p, g2, b2, (float*)d_out);
}

// Round 9
// 438.093 us; speedup vs baseline: 1.0329x; 1.0329x over previous
//
#include <hip/hip_runtime.h>
#include <stdint.h>

// Problem constants (DGCNN propagation). Inputs/outputs are FLOAT32 (per the
// reference's jnp.float32 setup_inputs); internals use bf16 MFMA (2% threshold).
#define B_   16
#define CIN  384     // C
#define GS   4096    // source points (power of 2 -> maskable)
#define GD   1024    // query points  (power of 2 -> maskable)
#define M1   512     // block1 out channels
#define K2C  512     // block2 in channels (= M1)
#define M2   384     // block2 out channels (= C)
#define ROWS2 768    // stacked block2 GEMM rows (W2a on top of W2d)
#define NEG  0.2f
#define EPS_ 1e-5f

typedef __bf16 bf16x8 __attribute__((ext_vector_type(8)));
typedef float  f32x4  __attribute__((ext_vector_type(4)));
typedef float  f32x2  __attribute__((ext_vector_type(2)));
typedef unsigned long long u64k;

__device__ __forceinline__ float bf2f(ushort u) {
  uint32_t v = ((uint32_t)u) << 16;
  return __builtin_bit_cast(float, v);
}
__device__ __forceinline__ ushort f2bf(float f) {
  uint32_t x = __builtin_bit_cast(uint32_t, f);
  x += 0x7FFFu + ((x >> 16) & 1u);
  return (ushort)(x >> 16);
}

// Packed dual-f32 ops (CDNA full-rate packed fp32). Each half is an ordinary
// IEEE f32 op -> bit-identical to scalar mul/add in the same order.
__device__ __forceinline__ f32x2 pk_mul(f32x2 a, f32x2 b) {
  f32x2 d; asm("v_pk_mul_f32 %0, %1, %2" : "=v"(d) : "v"(a), "v"(b)); return d;
}
__device__ __forceinline__ f32x2 pk_add(f32x2 a, f32x2 b) {
  f32x2 d; asm("v_pk_add_f32 %0, %1, %2" : "=v"(d) : "v"(a), "v"(b)); return d;
}
__device__ __forceinline__ f32x2 pk_fma(f32x2 a, f32x2 b, f32x2 c) {
  f32x2 d; asm("v_pk_fma_f32 %0, %1, %2, %3" : "=v"(d) : "v"(a), "v"(b), "v"(c)); return d;
}

// async global->LDS, 16B per lane. Dest must be wave-uniform base; HW adds lane*16.
__device__ __forceinline__ void gload16(const void* g, void* l) {
  __builtin_amdgcn_global_load_lds(
      (const __attribute__((address_space(1))) void*)g,
      (__attribute__((address_space(3))) void*)l, 16, 0, 0);
}

// ---------------- fused prep: weight split/convert + s2 tables (one launch) ----------------
// blocks 0..767: W1 (Kh=384); 768..1535: W2 (Kh=512); 1536..1855: s2 tables.
__global__ void k_prep(const float* __restrict__ W1, const float* __restrict__ W2,
                       ushort* __restrict__ W1a, ushort* __restrict__ W1d,
                       ushort* __restrict__ W2a, ushort* __restrict__ W2d,
                       const float* __restrict__ cs, const float* __restrict__ cqv,
                       float* __restrict__ s2s, float* __restrict__ s2q) {
#pragma clang fp contract(off)
  int blk = blockIdx.x;
  if (blk < 768) {
    int t = blk * 256 + threadIdx.x;
    int o = t / 384, c = t % 384;
    float wa = W1[(size_t)o * 768 + c];
    float wb = W1[(size_t)o * 768 + 384 + c];
    W1a[t] = f2bf(wa);
    W1d[t] = f2bf(wb - wa);
  } else if (blk < 1536) {
    int t = (blk - 768) * 256 + threadIdx.x;
    int o = t / 512, c = t % 512;
    float wa = W2[(size_t)o * 1024 + c];
    float wb = W2[(size_t)o * 1024 + 512 + c];
    W2a[t] = f2bf(wa);
    W2d[t] = f2bf(wb - wa);
  } else {
    int u = blk - 1536;                 // [0, 320): 16 batches x 20 blocks
    int b = u / 20;
    int i = (u % 20) * 256 + threadIdx.x;
    if (i < GS) {
      const float* cb = cs + (size_t)b * 3 * GS;
      float x = cb[i], y = cb[GS + i], z = cb[2 * GS + i];
      s2s[(size_t)b * GS + i] = (x * x + y * y) + z * z;
    } else {
      int j = i - GS;
      const float* cb = cqv + (size_t)b * 3 * GD;
      float x = cb[j], y = cb[GD + j], z = cb[2 * GD + j];
      s2q[(size_t)b * GD + j] = (x * x + y * y) + z * z;
    }
  }
}

// ---------------- kNN: wave-per-2-queries, u64-key sort4+bitonic-merge top-4 ----------------
// Distance values bit-identical to the verified serial version (see r1/r3 notes):
// s2 precomputed, dot via pk ops, d = pk_fma(dot,-2,q2+s2) == (q2+s2)-2*dot exactly.
// Selection: key = (monotone d bits, j) as u64 -> lex (d, idx) order == jax top_k
// tie-break (d never -0.0: q2+s2 >= 0, exact-zero fma -> +0.0 in RNE).
// Each wave processes TWO queries against the same candidate stream: the 4
// float4 loads per iteration are shared and the two independent sort/merge
// chains double ILP. Loads double-buffered (2-deep unroll, no register copies).
__device__ __forceinline__ uint32_t dmap(float d) {
  uint32_t u = __builtin_bit_cast(uint32_t, d);
  return u ^ (((uint32_t)((int32_t)u >> 31)) | 0x80000000u);  // monotone map f32 -> u32
}
__device__ __forceinline__ u64k mkkey(uint32_t hi, uint32_t lo) {
  uint2 t; t.x = lo; t.y = hi;               // register-pair build: no shift/or
  return __builtin_bit_cast(u64k, t);
}
__device__ __forceinline__ void kce(u64k& a, u64k& b) {
  bool c = b < a;
  u64k lo = c ? b : a, hi = c ? a : b;
  a = lo; b = hi;
}
__device__ __forceinline__ void klmin(u64k& a, u64k b) { a = b < a ? b : a; }

template<int GSRC>
__global__ __launch_bounds__(256) void k_knn(const float* __restrict__ cq,
                                             const float* __restrict__ ck,
                                             const float* __restrict__ s2qry,
                                             const float* __restrict__ s2src,
                                             int* __restrict__ idx) {
  constexpr int ITERS = GSRC / 256;
  static_assert(ITERS % 2 == 0, "even iteration count required for 2-deep unroll");
  int tid = threadIdx.x;
  int lane = tid & 63, wv = tid >> 6;
  int b = blockIdx.y;
  int qA = blockIdx.x * 8 + wv * 2;     // two queries per wave
  int qB = qA + 1;
  const float* cqb = cq + (size_t)b * 3 * GD;
  const float* ckb = ck + (size_t)b * 3 * GSRC;
  const float* s2b = s2src + (size_t)b * GSRC;
  float qxA = cqb[qA], qyA = cqb[GD + qA], qzA = cqb[2 * GD + qA];
  float qxB = cqb[qB], qyB = cqb[GD + qB], qzB = cqb[2 * GD + qB];
  float q2A = s2qry[(size_t)b * GD + qA];
  float q2B = s2qry[(size_t)b * GD + qB];
  f32x2 qxpA = {qxA, qxA}, qypA = {qyA, qyA}, qzpA = {qzA, qzA}, q2pA = {q2A, q2A};
  f32x2 qxpB = {qxB, qxB}, qypB = {qyB, qyB}, qzpB = {qzB, qzB}, q2pB = {q2B, q2B};
  f32x2 m2p = {-2.f, -2.f};

  u64k kA0 = ~0ull, kA1 = ~0ull, kA2 = ~0ull, kA3 = ~0ull;  // sorted-4 asc (query A)
  u64k kB0 = ~0ull, kB1 = ~0ull, kB2 = ~0ull, kB3 = ~0ull;  // sorted-4 asc (query B)

#define KNN_Q(QXP, QYP, QZP, Q2P, K0, K1, K2, K3)                              \
  {                                                                            \
    f32x2 dotl = pk_add(pk_add(pk_mul(QXP, xl), pk_mul(QYP, yl)), pk_mul(QZP, zl)); \
    f32x2 doth = pk_add(pk_add(pk_mul(QXP, xh), pk_mul(QYP, yh)), pk_mul(QZP, zh)); \
    f32x2 dl = pk_fma(dotl, m2p, pk_add(Q2P, sl));                             \
    f32x2 dh = pk_fma(doth, m2p, pk_add(Q2P, sh));                             \
    u64k n0 = mkkey(dmap(dl.x), j0u);                                          \
    u64k n1 = mkkey(dmap(dl.y), j0u + 1);                                      \
    u64k n2 = mkkey(dmap(dh.x), j0u + 2);                                      \
    u64k n3 = mkkey(dmap(dh.y), j0u + 3);                                      \
    kce(n0, n1); kce(n2, n3); kce(n0, n2); kce(n1, n3); kce(n1, n2);           \
    klmin(K0, n3); klmin(K1, n2); klmin(K2, n1); klmin(K3, n0);                \
    kce(K0, K2); kce(K1, K3); kce(K0, K1); kce(K2, K3);                        \
  }

#define KNN_STEP(Xv, Yv, Zv, Sv, J0)                                           \
  {                                                                            \
    f32x2 xl = {Xv.x, Xv.y}, xh = {Xv.z, Xv.w};                                \
    f32x2 yl = {Yv.x, Yv.y}, yh = {Yv.z, Yv.w};                                \
    f32x2 zl = {Zv.x, Zv.y}, zh = {Zv.z, Zv.w};                                \
    f32x2 sl = {Sv.x, Sv.y}, sh = {Sv.z, Sv.w};                                \
    uint32_t j0u = (uint32_t)(J0);                                             \
    KNN_Q(qxpA, qypA, qzpA, q2pA, kA0, kA1, kA2, kA3);                         \
    KNN_Q(qxpB, qypB, qzpB, q2pB, kB0, kB1, kB2, kB3);                         \
  }

#define KNN_LOAD(Xv, Yv, Zv, Sv, J)                                            \
  {                                                                            \
    Xv = *reinterpret_cast<const float4*>(ckb + (J));                          \
    Yv = *reinterpret_cast<const float4*>(ckb + GSRC + (J));                   \
    Zv = *reinterpret_cast<const float4*>(ckb + 2 * GSRC + (J));               \
    Sv = *reinterpret_cast<const float4*>(s2b + (J));                          \
  }

  int base = lane * 4;
  float4 X0, Y0, Z0, S0, X1, Y1, Z1, S1;
  KNN_LOAD(X0, Y0, Z0, S0, base);
  for (int it = 0; it < ITERS; it += 2) {
    int j0 = it * 256 + base;
    KNN_LOAD(X1, Y1, Z1, S1, j0 + 256);           // prefetch it+1 (always valid)
    KNN_STEP(X0, Y0, Z0, S0, j0);
    if (it + 2 < ITERS) KNN_LOAD(X0, Y0, Z0, S0, j0 + 512);  // prefetch it+2
    KNN_STEP(X1, Y1, Z1, S1, j0 + 256);
  }
#undef KNN_STEP
#undef KNN_Q
#undef KNN_LOAD

  // 6-step butterfly: merge two sorted 4-lists -> lowest 4 (bitonic, lex order),
  // run independently for both queries.
#pragma unroll
  for (int off = 1; off < 64; off <<= 1) {
    u64k p0 = __shfl_xor(kA0, off), p1 = __shfl_xor(kA1, off);
    u64k p2 = __shfl_xor(kA2, off), p3 = __shfl_xor(kA3, off);
    klmin(kA0, p3); klmin(kA1, p2); klmin(kA2, p1); klmin(kA3, p0);
    kce(kA0, kA2); kce(kA1, kA3); kce(kA0, kA1); kce(kA2, kA3);
    u64k r0 = __shfl_xor(kB0, off), r1 = __shfl_xor(kB1, off);
    u64k r2 = __shfl_xor(kB2, off), r3 = __shfl_xor(kB3, off);
    klmin(kB0, r3); klmin(kB1, r2); klmin(kB2, r1); klmin(kB3, r0);
    kce(kB0, kB2); kce(kB1, kB3); kce(kB0, kB1); kce(kB2, kB3);
  }
  if (lane == 0) {
    int4 ra;
    ra.x = (int)(uint32_t)kA0; ra.y = (int)(uint32_t)kA1;
    ra.z = (int)(uint32_t)kA2; ra.w = (int)(uint32_t)kA3;
    *reinterpret_cast<int4*>(&idx[((size_t)b * GD + qA) * 4]) = ra;
    int4 rb;
    rb.x = (int)(uint32_t)kB0; rb.y = (int)(uint32_t)kB1;
    rb.z = (int)(uint32_t)kB2; rb.w = (int)(uint32_t)kB3;
    *reinterpret_cast<int4*>(&idx[((size_t)b * GD + qB) * 4]) = rb;
  }
}

// ---------------- fused transpose+convert GEMM: out[b] = W(MxK) * bf16(X32[b](KxN)) ----------------
// B-operand read DIRECTLY from the f32 [Kd][N] source: per K-tile, coalesced f32
// row loads + f2bf + transposed LDS write into padded [128][40] (the pitch-40
// b128 pattern verified in rounds 1-6). Eliminates the standalone transpose
// kernels + their intermediate buffer traffic. A-side: verified gload16 linear.
// Values bit-identical: same f2bf on the same f32 inputs, same MFMA order.
template<bool OUT_BF16>
__global__ __launch_bounds__(256) void k_gemmF(const ushort* __restrict__ W,
                                               const float* __restrict__ X32,
                                               void* __restrict__ outv,
                                               int M, int Kd, int N) {
  __shared__ __align__(16) ushort As[128 * 32];  // 8 KB, linear (gload16 dest)
  __shared__ __align__(16) ushort Bs[128 * 40];  // 10 KB, padded (b128-aligned rows)
  int b = blockIdx.z;
  const float* X = X32 + (size_t)b * Kd * N;
  int m0 = blockIdx.y * 128, n0 = blockIdx.x * 128;
  int tid = threadIdx.x;
  int w = tid >> 6, lane = tid & 63;
  int lr = lane & 15, lq = lane >> 4;
  int mw = (w >> 1) * 64, nw = (w & 1) * 64;
  int r0 = tid >> 2, c0 = tid & 3;

  ushort* dA0 = As + w * 512;
  ushort* dA1 = As + 2048 + w * 512;
  const ushort* gA0 = W + (size_t)(m0 + r0) * Kd + c0 * 8;
  const ushort* gA1 = W + (size_t)(m0 + r0 + 64) * Kd + c0 * 8;

  int bn = tid & 127;          // n within tile (B staging)
  int bm = tid >> 7;           // k-pair group 0/1

  f32x4 zero = {0.f, 0.f, 0.f, 0.f};
  f32x4 acc[4][4];
#pragma unroll
  for (int mi = 0; mi < 4; mi++)
#pragma unroll
    for (int ni = 0; ni < 4; ni++) acc[mi][ni] = zero;

  int nk = Kd / 32;
  for (int kt = 0; kt < nk; kt++) {
    int kk = kt * 32;
    __syncthreads();                    // prev-iter LDS reads done
    gload16(gA0 + kk, dA0);
    gload16(gA1 + kk, dA1);
#pragma unroll
    for (int pp = 0; pp < 8; pp++) {
      int m = pp * 2 + bm;                       // k-pair index 0..15
      int k = kk + 2 * m;
      float va = X[(size_t)k * N + n0 + bn];
      float vb = X[(size_t)(k + 1) * N + n0 + bn];
      ushort2 pkv; pkv.x = f2bf(va); pkv.y = f2bf(vb);
      *reinterpret_cast<ushort2*>(&Bs[bn * 40 + 2 * m]) = pkv;
    }
    __syncthreads();
    bf16x8 af[4], bfr[4];
#pragma unroll
    for (int mi = 0; mi < 4; mi++)
      af[mi] = *reinterpret_cast<const bf16x8*>(&As[(mw + mi * 16 + lr) * 32 + lq * 8]);
#pragma unroll
    for (int ni = 0; ni < 4; ni++)
      bfr[ni] = *reinterpret_cast<const bf16x8*>(&Bs[(nw + ni * 16 + lr) * 40 + lq * 8]);
#pragma unroll
    for (int mi = 0; mi < 4; mi++)
#pragma unroll
      for (int ni = 0; ni < 4; ni++)
        acc[mi][ni] = __builtin_amdgcn_mfma_f32_16x16x32_bf16(af[mi], bfr[ni], acc[mi][ni], 0, 0, 0);
  }
#pragma unroll
  for (int mi = 0; mi < 4; mi++) {
    int m = m0 + mw + mi * 16 + lq * 4;
#pragma unroll
    for (int ni = 0; ni < 4; ni++) {
      int n = n0 + nw + ni * 16 + lr;
#pragma unroll
      for (int r = 0; r < 4; r++) {
        size_t off = (size_t)b * M * N + (size_t)(m + r) * N + n;
        if constexpr (OUT_BF16) ((ushort*)outv)[off] = f2bf(acc[mi][ni][r]);
        else                    ((float*)outv)[off] = acc[mi][ni][r];
      }
    }
  }
}

// ---------------- bf16-input MFMA GEMM (m97 structure, verified r7): GEMM2 ----------------
template<bool OUT_BF16>
__global__ __launch_bounds__(256) void k_gemm(const ushort* __restrict__ W,
                                              const ushort* __restrict__ Xt,
                                              void* __restrict__ outv,
                                              int M, int Kd, int N) {
  __shared__ __align__(16) ushort As[128 * 32];  // 8 KB, linear
  __shared__ __align__(16) ushort Bs[128 * 32];  // 8 KB, linear
  int b = blockIdx.z;
  const ushort* X = Xt + (size_t)b * N * Kd;
  int m0 = blockIdx.y * 128, n0 = blockIdx.x * 128;
  int tid = threadIdx.x;
  int w = tid >> 6, lane = tid & 63;
  int lr = lane & 15, lq = lane >> 4;
  int mw = (w >> 1) * 64, nw = (w & 1) * 64;
  int r0 = tid >> 2, c0 = tid & 3;

  ushort* dA0 = As + w * 512;
  ushort* dA1 = As + 2048 + w * 512;
  ushort* dB0 = Bs + w * 512;
  ushort* dB1 = Bs + 2048 + w * 512;
  const ushort* gA0 = W + (size_t)(m0 + r0) * Kd + c0 * 8;
  const ushort* gA1 = W + (size_t)(m0 + r0 + 64) * Kd + c0 * 8;
  const ushort* gB0 = X + (size_t)(n0 + r0) * Kd + c0 * 8;
  const ushort* gB1 = X + (size_t)(n0 + r0 + 64) * Kd + c0 * 8;

  f32x4 zero = {0.f, 0.f, 0.f, 0.f};
  f32x4 acc[4][4];
#pragma unroll
  for (int mi = 0; mi < 4; mi++)
#pragma unroll
    for (int ni = 0; ni < 4; ni++) acc[mi][ni] = zero;

  int nk = Kd / 32;
  for (int kt = 0; kt < nk; kt++) {
    int kk = kt * 32;
    __syncthreads();
    gload16(gA0 + kk, dA0);
    gload16(gA1 + kk, dA1);
    gload16(gB0 + kk, dB0);
    gload16(gB1 + kk, dB1);
    __syncthreads();
    bf16x8 af[4], bfr[4];
#pragma unroll
    for (int mi = 0; mi < 4; mi++)
      af[mi] = *reinterpret_cast<const bf16x8*>(&As[(mw + mi * 16 + lr) * 32 + lq * 8]);
#pragma unroll
    for (int ni = 0; ni < 4; ni++)
      bfr[ni] = *reinterpret_cast<const bf16x8*>(&Bs[(nw + ni * 16 + lr) * 32 + lq * 8]);
#pragma unroll
    for (int mi = 0; mi < 4; mi++)
#pragma unroll
      for (int ni = 0; ni < 4; ni++)
        acc[mi][ni] = __builtin_amdgcn_mfma_f32_16x16x32_bf16(af[mi], bfr[ni], acc[mi][ni], 0, 0, 0);
  }
#pragma unroll
  for (int mi = 0; mi < 4; mi++) {
    int m = m0 + mw + mi * 16 + lq * 4;
#pragma unroll
    for (int ni = 0; ni < 4; ni++) {
      int n = n0 + nw + ni * 16 + lr;
#pragma unroll
      for (int r = 0; r < 4; r++) {
        size_t off = (size_t)b * M * N + (size_t)(m + r) * N + n;
        if constexpr (OUT_BF16) ((ushort*)outv)[off] = f2bf(acc[mi][ni][r]);
        else                    ((float*)outv)[off] = acc[mi][ni][r];
      }
    }
  }
}

// ---------------- GN1 stats + Ysel pass: y = bf16(A)[gather] + Bq ----------------
// Per (o,g): accumulate sum/ssq AND write Ysel[o][g] = (gamma[o]>=0 ? max_k y : min_k y).
// Monotonicity of t(y)=leaky((y-mean)*rstd*ga+be) in y (rstd>0) makes
// max_k t(y_k) == t(Ysel) exactly (weakly-monotone rounded op chain).
// A-row (8KB) and idx table (16KB) staged in LDS: coalesced global reads only.
__global__ __launch_bounds__(256) void k_stats1y(const ushort* __restrict__ A,
                                                 const float* __restrict__ Bq,
                                                 const int* __restrict__ idx1,
                                                 const float* __restrict__ gam,
                                                 float* __restrict__ Ysel,
                                                 float* __restrict__ part) {
  __shared__ __align__(16) ushort Arow[GS];   // 8 KB
  __shared__ __align__(16) int ids[GD * 4];   // 16 KB
  __shared__ float rs[256], rq[256];
  int s = blockIdx.x, grp = blockIdx.y, b = blockIdx.z;
  int tid = threadIdx.x;
  for (int i = tid; i < GD; i += 256) {
    int4 v = *reinterpret_cast<const int4*>(&idx1[((size_t)b * GD + i) * 4]);
    v.x &= (GS - 1); v.y &= (GS - 1); v.z &= (GS - 1); v.w &= (GS - 1);
    *reinterpret_cast<int4*>(&ids[i * 4]) = v;
  }
  float sum = 0.f, ssq = 0.f;
  for (int oi = 0; oi < 16; oi++) {
    int o = grp * 128 + s * 16 + oi;
    const ushort* Ar = A + ((size_t)b * M1 + o) * GS;
    __syncthreads();  // prev-iter gathers done (also covers ids staging on oi=0)
#pragma unroll
    for (int i = tid * 8; i < GS; i += 2048)
      *reinterpret_cast<uint4*>(&Arow[i]) = *reinterpret_cast<const uint4*>(&Ar[i]);
    __syncthreads();
    const float* Br = Bq + ((size_t)b * M1 + o) * GD;
    float* Yr = Ysel + ((size_t)b * M1 + o) * GD;
    float sgn = gam[o];
    for (int g = tid; g < GD; g += 256) {
      int4 id = *reinterpret_cast<const int4*>(&ids[g * 4]);
      float base = Br[g];
      float y0 = bf2f(Arow[id.x]) + base;
      float y1 = bf2f(Arow[id.y]) + base;
      float y2 = bf2f(Arow[id.z]) + base;
      float y3 = bf2f(Arow[id.w]) + base;
      sum += y0 + y1 + y2 + y3;
      ssq += y0 * y0 + y1 * y1 + y2 * y2 + y3 * y3;
      float mx = fmaxf(fmaxf(y0, y1), fmaxf(y2, y3));
      float mn = fminf(fminf(y0, y1), fminf(y2, y3));
      Yr[g] = (sgn >= 0.f) ? mx : mn;
    }
  }
  rs[tid] = sum; rq[tid] = ssq;
  __syncthreads();
  for (int t = 128; t > 0; t >>= 1) {
    if (tid < t) { rs[tid] += rs[tid + t]; rq[tid] += rq[tid + t]; }
    __syncthreads();
  }
  if (tid == 0) {
    int key = ((b * 4 + grp) * 8 + s) * 2;
    part[key] = rs[0]; part[key + 1] = rq[0];
  }
}

// ---------------- GN2 stats + Ysel pass (stacked Y2 layout [b][768][1024]) ----------------
// rows 0..383 = A2 (W2a*hT), rows 384..767 = B2q (W2d*hT). 96-ch groups, 12 ch/split.
__global__ __launch_bounds__(256) void k_stats2y(const float* __restrict__ Y2,
                                                 const int* __restrict__ idx2,
                                                 const float* __restrict__ gam,
                                                 float* __restrict__ Ysel,
                                                 float* __restrict__ part) {
  __shared__ __align__(16) float Arow[GD];    // 4 KB
  __shared__ __align__(16) int ids[GD * 4];   // 16 KB
  __shared__ float rs[256], rq[256];
  int s = blockIdx.x, grp = blockIdx.y, b = blockIdx.z;
  int tid = threadIdx.x;
  for (int i = tid; i < GD; i += 256) {
    int4 v = *reinterpret_cast<const int4*>(&idx2[((size_t)b * GD + i) * 4]);
    v.x &= (GD - 1); v.y &= (GD - 1); v.z &= (GD - 1); v.w &= (GD - 1);
    *reinterpret_cast<int4*>(&ids[i * 4]) = v;
  }
  float sum = 0.f, ssq = 0.f;
  for (int oi = 0; oi < 12; oi++) {
    int o = grp * 96 + s * 12 + oi;
    const float* Ar = Y2 + ((size_t)b * ROWS2 + o) * GD;
    __syncthreads();
#pragma unroll
    for (int i = tid * 4; i < GD; i += 1024)
      *reinterpret_cast<float4*>(&Arow[i]) = *reinterpret_cast<const float4*>(&Ar[i]);
    __syncthreads();
    const float* Br = Y2 + ((size_t)b * ROWS2 + 384 + o) * GD;
    float* Yr = Ysel + ((size_t)b * M2 + o) * GD;
    float sgn = gam[o];
    for (int g = tid; g < GD; g += 256) {
      int4 id = *reinterpret_cast<const int4*>(&ids[g * 4]);
      float base = Br[g];
      float y0 = Arow[id.x] + base;
      float y1 = Arow[id.y] + base;
      float y2 = Arow[id.z] + base;
      float y3 = Arow[id.w] + base;
      sum += y0 + y1 + y2 + y3;
      ssq += y0 * y0 + y1 * y1 + y2 * y2 + y3 * y3;
      float mx = fmaxf(fmaxf(y0, y1), fmaxf(y2, y3));
      float mn = fminf(fminf(y0, y1), fminf(y2, y3));
      Yr[g] = (sgn >= 0.f) ? mx : mn;
    }
  }
  rs[tid] = sum; rq[tid] = ssq;
  __syncthreads();
  for (int t = 128; t > 0; t >>= 1) {
    if (tid < t) { rs[tid] += rs[tid + t]; rq[tid] += rq[tid + t]; }
    __syncthreads();
  }
  if (tid == 0) {
    int key = ((b * 4 + grp) * 8 + s) * 2;
    part[key] = rs[0]; part[key + 1] = rq[0];
  }
}

// ---------------- h = leaky(GN(Ysel)); statsfin inlined (identical arith order) ----------------
__global__ void k_h2(const float* __restrict__ Ysel, const float* __restrict__ part,
                     const float* __restrict__ gam, const float* __restrict__ bet,
                     ushort* __restrict__ hT) {
  __shared__ ushort tile[64][66];  // pitch 66: conflict-free column reads
  int g0 = blockIdx.x * 64, o0 = blockIdx.y * 64, b = blockIdx.z;
  int tid = threadIdx.x;
  int tkey = b * 4 + (o0 >> 7);
  float s = 0.f, q = 0.f;
#pragma unroll
  for (int i = 0; i < 8; i++) { s += part[(tkey * 8 + i) * 2]; q += part[(tkey * 8 + i) * 2 + 1]; }
  float mean = s * (1.0f / 524288.0f);
  float var = q * (1.0f / 524288.0f) - mean * mean;
  float rstd = 1.0f / sqrtf(fmaxf(var, 0.0f) + EPS_);
  int gx = tid & 63, oy = tid >> 6;
#pragma unroll
  for (int oi = 0; oi < 16; oi++) {
    int ol = oi * 4 + oy;
    int o = o0 + ol;
    float y = Ysel[((size_t)b * M1 + o) * GD + g0 + gx];
    float v = (y - mean) * rstd * gam[o] + bet[o];
    v = v >= 0.f ? v : NEG * v;
    tile[ol][gx] = f2bf(v);
  }
  __syncthreads();
  int col = tid & 63, r4 = tid >> 6;
#pragma unroll
  for (int i = 0; i < 16; i++) {
    int gl = i * 4 + r4;
    hT[((size_t)b * GD + g0 + gl) * K2C + o0 + col] = tile[col][gl];
  }
}

// ---------------- final: out = leaky(GN2(Ysel2)), statsfin inlined -> f32 ----------------
__global__ void k_out2(const float* __restrict__ Ysel2, const float* __restrict__ part,
                       const float* __restrict__ gam, const float* __restrict__ bet,
                       float* __restrict__ out) {
  int b = blockIdx.z, o = blockIdx.y;
  int g = blockIdx.x * 256 + threadIdx.x;
  int tkey = b * 4 + o / 96;
  float s = 0.f, q = 0.f;
#pragma unroll
  for (int i = 0; i < 8; i++) { s += part[(tkey * 8 + i) * 2]; q += part[(tkey * 8 + i) * 2 + 1]; }
  float mean = s * (1.0f / 393216.0f);
  float var = q * (1.0f / 393216.0f) - mean * mean;
  float rstd = 1.0f / sqrtf(fmaxf(var, 0.0f) + EPS_);
  float y = Ysel2[((size_t)b * M2 + o) * GD + g];
  float v = (y - mean) * rstd * gam[o] + bet[o];
  v = v >= 0.f ? v : NEG * v;
  out[((size_t)b * M2 + o) * GD + g] = v;
}

extern "C" void kernel_launch(void* const* d_in, const int* in_sizes, int n_in,
                              void* d_out, int out_size, void* d_ws, size_t ws_size,
                              hipStream_t stream) {
  (void)in_sizes; (void)n_in; (void)out_size;
  const float* coor  = (const float*)d_in[0];  // [16][3][4096] f32
  const float* f     = (const float*)d_in[1];  // [16][384][4096]
  const float* coorq = (const float*)d_in[2];  // [16][3][1024]
  const float* fq    = (const float*)d_in[3];  // [16][384][1024]
  const float* W1    = (const float*)d_in[4];  // [512][768]
  const float* g1    = (const float*)d_in[5];
  const float* b1    = (const float*)d_in[6];
  const float* W2    = (const float*)d_in[7];  // [384][1024]
  const float* g2    = (const float*)d_in[8];
  const float* b2    = (const float*)d_in[9];

  // Required workspace ~182.5 MB (internal buffer layout unchanged; skip cleanly if short).
  if (ws_size < 182468608u) return;

  char* ws = (char*)d_ws;
  int*    idx1 = (int*)(ws + 0);            // 256 KB
  int*    idx2 = (int*)(ws + 0x40000);      // 256 KB
  float*  s1p  = (float*)(ws + 0x80000);    // 4 KB
  float*  s2p  = (float*)(ws + 0x82000);
  ushort* W1a  = (ushort*)(ws + 0x84000);           // 512*384 bf16
  ushort* W1d  = W1a + (size_t)512 * 384;
  ushort* W2a  = W1d + (size_t)512 * 384;           // 384*512 (W2d contiguous after -> stacked M=768 GEMM)
  ushort* W2d  = W2a + (size_t)384 * 512;
  ushort* fT   = W2d + (size_t)384 * 512;           // region reused: Y2/Ysel1 aliases (fT itself now dead)
  ushort* fqT  = fT + (size_t)B_ * GS * CIN;        // dead (transpose fused into GEMM1s)
  ushort* Abuf = fqT + (size_t)B_ * GD * CIN;       // [16][512][4096] bf16, 67.1 MB
  float*  Bq   = (float*)(Abuf + (size_t)B_ * M1 * GS);   // [16][512][1024] f32, 33.6 MB
  ushort* hT   = (ushort*)((char*)Bq + (size_t)B_ * M1 * GD * 4); // [16][1024][512] bf16, 16.8 MB
  // Y2 = stacked block2 GEMM output [16][768][1024] f32 (rows 0..383 = A2, 384..767 = B2q).
  float*  Y2   = (float*)fT;
  // Ysel1 aliases the same region (consumed by k_h2 BEFORE the stacked GEMM overwrites).
  float*  Ysel1 = (float*)fT;                       // [16][512][1024] f32, 33.6 MB
  // Ysel2 aliases dead Abuf (Abuf's last reader is k_stats1y).
  float*  Ysel2 = (float*)Abuf;                     // [16][384][1024] f32, 25.2 MB
  // s2 tables live in the not-yet-written hT region (read only by k_knn, which
  // completes before k_h2 writes hT -> stream-ordered safe; no extra ws needed).
  float*  s2s  = (float*)hT;                        // [16][4096] f32, 256 KB
  float*  s2q  = s2s + (size_t)B_ * GS;             // [16][1024] f32, 64 KB

  // 1. fused prep: weight split/convert + s2 tables (one launch)
  k_prep<<<dim3(1856), 256, 0, stream>>>(W1, W2, W1a, W1d, W2a, W2d,
                                         coor, coorq, s2s, s2q);

  // 2. kNN index sets (2 queries/wave, shared candidate loads, double-buffered)
  k_knn<GS><<<dim3(GD / 8, B_), 256, 0, stream>>>(coorq, coor, s2q, s2s, idx1);
  k_knn<GD><<<dim3(GD / 8, B_), 256, 0, stream>>>(coorq, coorq, s2q, s2q, idx2);

  // 3. block1 GEMMs with fused transpose+convert (read f/fq f32 directly)
  k_gemmF<true ><<<dim3(GS / 128, M1 / 128, B_), 256, 0, stream>>>(W1a, f, Abuf, M1, CIN, GS);
  k_gemmF<false><<<dim3(GD / 128, M1 / 128, B_), 256, 0, stream>>>(W1d, fq, Bq, M1, CIN, GD);

  // 4. GN1 stats + Ysel1 (single gather pass), then streaming h transform (statsfin inline)
  k_stats1y<<<dim3(8, 4, B_), 256, 0, stream>>>(Abuf, Bq, idx1, g1, Ysel1, s1p);
  k_h2<<<dim3(GD / 64, M1 / 64, B_), 256, 0, stream>>>(Ysel1, s1p, g1, b1, hT);

  // 5. block2 GEMM, stacked: [W2a; W2d] (M=768) * hT -> Y2 (one pass over hT)
  k_gemm<false><<<dim3(GD / 128, ROWS2 / 128, B_), 256, 0, stream>>>(W2a, hT, Y2, ROWS2, K2C, GD);

  // 6. GN2 stats + Ysel2 (single gather pass), then streaming final output (statsfin inline)
  k_stats2y<<<dim3(8, 4, B_), 256, 0, stream>>>(Y2, idx2, g2, Ysel2, s2p);
  k_out2<<<dim3(GD / 256, M2, B_), 256, 0, stream>>>(Ysel2, s2p, g2, b2, (float*)d_out);
}

// Round 10
// 435.593 us; speedup vs baseline: 1.0388x; 1.0057x over previous
//
#include <hip/hip_runtime.h>
#include <stdint.h>

// Problem constants (DGCNN propagation). Inputs/outputs are FLOAT32 (per the
// reference's jnp.float32 setup_inputs); internals use bf16 MFMA (2% threshold).
#define B_   16
#define CIN  384     // C
#define GS   4096    // source points (power of 2 -> maskable)
#define GD   1024    // query points  (power of 2 -> maskable)
#define M1   512     // block1 out channels
#define K2C  512     // block2 in channels (= M1)
#define M2   384     // block2 out channels (= C)
#define ROWS2 768    // stacked block2 GEMM rows (W2a on top of W2d)
#define NEG  0.2f
#define EPS_ 1e-5f

typedef __bf16 bf16x8 __attribute__((ext_vector_type(8)));
typedef float  f32x4  __attribute__((ext_vector_type(4)));
typedef float  f32x2  __attribute__((ext_vector_type(2)));
typedef unsigned long long u64k;

__device__ __forceinline__ float bf2f(ushort u) {
  uint32_t v = ((uint32_t)u) << 16;
  return __builtin_bit_cast(float, v);
}
__device__ __forceinline__ ushort f2bf(float f) {
  uint32_t x = __builtin_bit_cast(uint32_t, f);
  x += 0x7FFFu + ((x >> 16) & 1u);
  return (ushort)(x >> 16);
}

// Packed dual-f32 ops (CDNA full-rate packed fp32). Each half is an ordinary
// IEEE f32 op -> bit-identical to scalar mul/add in the same order.
__device__ __forceinline__ f32x2 pk_mul(f32x2 a, f32x2 b) {
  f32x2 d; asm("v_pk_mul_f32 %0, %1, %2" : "=v"(d) : "v"(a), "v"(b)); return d;
}
__device__ __forceinline__ f32x2 pk_add(f32x2 a, f32x2 b) {
  f32x2 d; asm("v_pk_add_f32 %0, %1, %2" : "=v"(d) : "v"(a), "v"(b)); return d;
}
__device__ __forceinline__ f32x2 pk_fma(f32x2 a, f32x2 b, f32x2 c) {
  f32x2 d; asm("v_pk_fma_f32 %0, %1, %2, %3" : "=v"(d) : "v"(a), "v"(b), "v"(c)); return d;
}

// async global->LDS, 16B per lane. Dest must be wave-uniform base; HW adds lane*16.
__device__ __forceinline__ void gload16(const void* g, void* l) {
  __builtin_amdgcn_global_load_lds(
      (const __attribute__((address_space(1))) void*)g,
      (__attribute__((address_space(3))) void*)l, 16, 0, 0);
}

// ---------------- fused prep: weight split/convert + s2 tables (one launch) ----------------
// blocks 0..767: W1 (Kh=384); 768..1535: W2 (Kh=512); 1536..1855: s2 tables.
__global__ void k_prep(const float* __restrict__ W1, const float* __restrict__ W2,
                       ushort* __restrict__ W1a, ushort* __restrict__ W1d,
                       ushort* __restrict__ W2a, ushort* __restrict__ W2d,
                       const float* __restrict__ cs, const float* __restrict__ cqv,
                       float* __restrict__ s2s, float* __restrict__ s2q) {
#pragma clang fp contract(off)
  int blk = blockIdx.x;
  if (blk < 768) {
    int t = blk * 256 + threadIdx.x;
    int o = t / 384, c = t % 384;
    float wa = W1[(size_t)o * 768 + c];
    float wb = W1[(size_t)o * 768 + 384 + c];
    W1a[t] = f2bf(wa);
    W1d[t] = f2bf(wb - wa);
  } else if (blk < 1536) {
    int t = (blk - 768) * 256 + threadIdx.x;
    int o = t / 512, c = t % 512;
    float wa = W2[(size_t)o * 1024 + c];
    float wb = W2[(size_t)o * 1024 + 512 + c];
    W2a[t] = f2bf(wa);
    W2d[t] = f2bf(wb - wa);
  } else {
    int u = blk - 1536;                 // [0, 320): 16 batches x 20 blocks
    int b = u / 20;
    int i = (u % 20) * 256 + threadIdx.x;
    if (i < GS) {
      const float* cb = cs + (size_t)b * 3 * GS;
      float x = cb[i], y = cb[GS + i], z = cb[2 * GS + i];
      s2s[(size_t)b * GS + i] = (x * x + y * y) + z * z;
    } else {
      int j = i - GS;
      const float* cb = cqv + (size_t)b * 3 * GD;
      float x = cb[j], y = cb[GD + j], z = cb[2 * GD + j];
      s2q[(size_t)b * GD + j] = (x * x + y * y) + z * z;
    }
  }
}

// ---------------- kNN: wave-per-2-queries, u64-key sort4+bitonic-merge top-4 ----------------
// Distance values bit-identical to the verified serial version (see r1/r3 notes):
// s2 precomputed, dot via pk ops, d = pk_fma(dot,-2,q2+s2) == (q2+s2)-2*dot exactly.
// Selection: key = (monotone d bits, j) as u64 -> lex (d, idx) order == jax top_k
// tie-break (d never -0.0: q2+s2 >= 0, exact-zero fma -> +0.0 in RNE).
// Each wave processes TWO queries against the same candidate stream: the 4
// float4 loads per iteration are shared and the two independent sort/merge
// chains double ILP. Loads double-buffered (2-deep unroll, no register copies).
__device__ __forceinline__ uint32_t dmap(float d) {
  uint32_t u = __builtin_bit_cast(uint32_t, d);
  return u ^ (((uint32_t)((int32_t)u >> 31)) | 0x80000000u);  // monotone map f32 -> u32
}
__device__ __forceinline__ u64k mkkey(uint32_t hi, uint32_t lo) {
  uint2 t; t.x = lo; t.y = hi;               // register-pair build: no shift/or
  return __builtin_bit_cast(u64k, t);
}
__device__ __forceinline__ void kce(u64k& a, u64k& b) {
  bool c = b < a;
  u64k lo = c ? b : a, hi = c ? a : b;
  a = lo; b = hi;
}
__device__ __forceinline__ void klmin(u64k& a, u64k b) { a = b < a ? b : a; }

template<int GSRC>
__global__ __launch_bounds__(256) void k_knn(const float* __restrict__ cq,
                                             const float* __restrict__ ck,
                                             const float* __restrict__ s2qry,
                                             const float* __restrict__ s2src,
                                             int* __restrict__ idx) {
  constexpr int ITERS = GSRC / 256;
  static_assert(ITERS % 2 == 0, "even iteration count required for 2-deep unroll");
  int tid = threadIdx.x;
  int lane = tid & 63, wv = tid >> 6;
  int b = blockIdx.y;
  int qA = blockIdx.x * 8 + wv * 2;     // two queries per wave
  int qB = qA + 1;
  const float* cqb = cq + (size_t)b * 3 * GD;
  const float* ckb = ck + (size_t)b * 3 * GSRC;
  const float* s2b = s2src + (size_t)b * GSRC;
  float qxA = cqb[qA], qyA = cqb[GD + qA], qzA = cqb[2 * GD + qA];
  float qxB = cqb[qB], qyB = cqb[GD + qB], qzB = cqb[2 * GD + qB];
  float q2A = s2qry[(size_t)b * GD + qA];
  float q2B = s2qry[(size_t)b * GD + qB];
  f32x2 qxpA = {qxA, qxA}, qypA = {qyA, qyA}, qzpA = {qzA, qzA}, q2pA = {q2A, q2A};
  f32x2 qxpB = {qxB, qxB}, qypB = {qyB, qyB}, qzpB = {qzB, qzB}, q2pB = {q2B, q2B};
  f32x2 m2p = {-2.f, -2.f};

  u64k kA0 = ~0ull, kA1 = ~0ull, kA2 = ~0ull, kA3 = ~0ull;  // sorted-4 asc (query A)
  u64k kB0 = ~0ull, kB1 = ~0ull, kB2 = ~0ull, kB3 = ~0ull;  // sorted-4 asc (query B)

#define KNN_Q(QXP, QYP, QZP, Q2P, K0, K1, K2, K3)                              \
  {                                                                            \
    f32x2 dotl = pk_add(pk_add(pk_mul(QXP, xl), pk_mul(QYP, yl)), pk_mul(QZP, zl)); \
    f32x2 doth = pk_add(pk_add(pk_mul(QXP, xh), pk_mul(QYP, yh)), pk_mul(QZP, zh)); \
    f32x2 dl = pk_fma(dotl, m2p, pk_add(Q2P, sl));                             \
    f32x2 dh = pk_fma(doth, m2p, pk_add(Q2P, sh));                             \
    u64k n0 = mkkey(dmap(dl.x), j0u);                                          \
    u64k n1 = mkkey(dmap(dl.y), j0u + 1);                                      \
    u64k n2 = mkkey(dmap(dh.x), j0u + 2);                                      \
    u64k n3 = mkkey(dmap(dh.y), j0u + 3);                                      \
    kce(n0, n1); kce(n2, n3); kce(n0, n2); kce(n1, n3); kce(n1, n2);           \
    klmin(K0, n3); klmin(K1, n2); klmin(K2, n1); klmin(K3, n0);                \
    kce(K0, K2); kce(K1, K3); kce(K0, K1); kce(K2, K3);                        \
  }

#define KNN_STEP(Xv, Yv, Zv, Sv, J0)                                           \
  {                                                                            \
    f32x2 xl = {Xv.x, Xv.y}, xh = {Xv.z, Xv.w};                                \
    f32x2 yl = {Yv.x, Yv.y}, yh = {Yv.z, Yv.w};                                \
    f32x2 zl = {Zv.x, Zv.y}, zh = {Zv.z, Zv.w};                                \
    f32x2 sl = {Sv.x, Sv.y}, sh = {Sv.z, Sv.w};                                \
    uint32_t j0u = (uint32_t)(J0);                                             \
    KNN_Q(qxpA, qypA, qzpA, q2pA, kA0, kA1, kA2, kA3);                         \
    KNN_Q(qxpB, qypB, qzpB, q2pB, kB0, kB1, kB2, kB3);                         \
  }

#define KNN_LOAD(Xv, Yv, Zv, Sv, J)                                            \
  {                                                                            \
    Xv = *reinterpret_cast<const float4*>(ckb + (J));                          \
    Yv = *reinterpret_cast<const float4*>(ckb + GSRC + (J));                   \
    Zv = *reinterpret_cast<const float4*>(ckb + 2 * GSRC + (J));               \
    Sv = *reinterpret_cast<const float4*>(s2b + (J));                          \
  }

  int base = lane * 4;
  float4 X0, Y0, Z0, S0, X1, Y1, Z1, S1;
  KNN_LOAD(X0, Y0, Z0, S0, base);
  for (int it = 0; it < ITERS; it += 2) {
    int j0 = it * 256 + base;
    KNN_LOAD(X1, Y1, Z1, S1, j0 + 256);           // prefetch it+1 (always valid)
    KNN_STEP(X0, Y0, Z0, S0, j0);
    if (it + 2 < ITERS) KNN_LOAD(X0, Y0, Z0, S0, j0 + 512);  // prefetch it+2
    KNN_STEP(X1, Y1, Z1, S1, j0 + 256);
  }
#undef KNN_STEP
#undef KNN_Q
#undef KNN_LOAD

  // 6-step butterfly: merge two sorted 4-lists -> lowest 4 (bitonic, lex order),
  // run independently for both queries.
#pragma unroll
  for (int off = 1; off < 64; off <<= 1) {
    u64k p0 = __shfl_xor(kA0, off), p1 = __shfl_xor(kA1, off);
    u64k p2 = __shfl_xor(kA2, off), p3 = __shfl_xor(kA3, off);
    klmin(kA0, p3); klmin(kA1, p2); klmin(kA2, p1); klmin(kA3, p0);
    kce(kA0, kA2); kce(kA1, kA3); kce(kA0, kA1); kce(kA2, kA3);
    u64k r0 = __shfl_xor(kB0, off), r1 = __shfl_xor(kB1, off);
    u64k r2 = __shfl_xor(kB2, off), r3 = __shfl_xor(kB3, off);
    klmin(kB0, r3); klmin(kB1, r2); klmin(kB2, r1); klmin(kB3, r0);
    kce(kB0, kB2); kce(kB1, kB3); kce(kB0, kB1); kce(kB2, kB3);
  }
  if (lane == 0) {
    int4 ra;
    ra.x = (int)(uint32_t)kA0; ra.y = (int)(uint32_t)kA1;
    ra.z = (int)(uint32_t)kA2; ra.w = (int)(uint32_t)kA3;
    *reinterpret_cast<int4*>(&idx[((size_t)b * GD + qA) * 4]) = ra;
    int4 rb;
    rb.x = (int)(uint32_t)kB0; rb.y = (int)(uint32_t)kB1;
    rb.z = (int)(uint32_t)kB2; rb.w = (int)(uint32_t)kB3;
    *reinterpret_cast<int4*>(&idx[((size_t)b * GD + qB) * 4]) = rb;
  }
}

// ---------------- fused transpose+convert GEMM: out[b] = W(MxK) * bf16(X32[b](KxN)) ----------------
// B-operand read DIRECTLY from the f32 [Kd][N] source. Conflict-free staging:
// Bs layout [4 kgroup][128 n][8 k] bf16. Thread (n=tid&127, g) loads 8 f32 at
// fixed n (each j-iteration is a fully coalesced 256B wave transaction),
// converts, and writes ONE 16B chunk at (g*128+n)*16 -> consecutive lanes hit
// consecutive 16B addresses = zero bank conflicts (the gload16 property).
// Fragment read Bs[(lq*128+n)*8]: lanes sweep n*4 mod 32, 2 lanes/bank = free.
// A-side: verified gload16 linear. Values bit-identical (same f2bf, same order).
template<bool OUT_BF16>
__global__ __launch_bounds__(256) void k_gemmF(const ushort* __restrict__ W,
                                               const float* __restrict__ X32,
                                               void* __restrict__ outv,
                                               int M, int Kd, int N) {
  __shared__ __align__(16) ushort As[128 * 32];   // 8 KB, linear (gload16 dest)
  __shared__ __align__(16) ushort Bs[4 * 128 * 8]; // 8 KB, [g][n][8] chunks
  int b = blockIdx.z;
  const float* X = X32 + (size_t)b * Kd * N;
  int m0 = blockIdx.y * 128, n0 = blockIdx.x * 128;
  int tid = threadIdx.x;
  int w = tid >> 6, lane = tid & 63;
  int lr = lane & 15, lq = lane >> 4;
  int mw = (w >> 1) * 64, nw = (w & 1) * 64;
  int r0 = tid >> 2, c0 = tid & 3;

  ushort* dA0 = As + w * 512;
  ushort* dA1 = As + 2048 + w * 512;
  const ushort* gA0 = W + (size_t)(m0 + r0) * Kd + c0 * 8;
  const ushort* gA1 = W + (size_t)(m0 + r0 + 64) * Kd + c0 * 8;

  int bn = tid & 127;          // n within tile (B staging)
  int bg = tid >> 7;           // k-group base 0/1 (handles bg and bg+2)
  const float* Xcol = X + n0 + bn;

  f32x4 zero = {0.f, 0.f, 0.f, 0.f};
  f32x4 acc[4][4];
#pragma unroll
  for (int mi = 0; mi < 4; mi++)
#pragma unroll
    for (int ni = 0; ni < 4; ni++) acc[mi][ni] = zero;

  int nk = Kd / 32;
  for (int kt = 0; kt < nk; kt++) {
    int kk = kt * 32;
    __syncthreads();                    // prev-iter LDS reads done
    gload16(gA0 + kk, dA0);
    gload16(gA1 + kk, dA1);
#pragma unroll
    for (int gg = 0; gg < 2; gg++) {
      int g = bg + gg * 2;              // k-group 0..3
      const float* Xg = Xcol + (size_t)(kk + g * 8) * N;
      float v0 = Xg[0];
      float v1 = Xg[(size_t)N];
      float v2 = Xg[(size_t)2 * N];
      float v3 = Xg[(size_t)3 * N];
      float v4 = Xg[(size_t)4 * N];
      float v5 = Xg[(size_t)5 * N];
      float v6 = Xg[(size_t)6 * N];
      float v7 = Xg[(size_t)7 * N];
      uint4 pkv;
      pkv.x = (uint32_t)f2bf(v0) | ((uint32_t)f2bf(v1) << 16);
      pkv.y = (uint32_t)f2bf(v2) | ((uint32_t)f2bf(v3) << 16);
      pkv.z = (uint32_t)f2bf(v4) | ((uint32_t)f2bf(v5) << 16);
      pkv.w = (uint32_t)f2bf(v6) | ((uint32_t)f2bf(v7) << 16);
      *reinterpret_cast<uint4*>(&Bs[(g * 128 + bn) * 8]) = pkv;
    }
    __syncthreads();
    bf16x8 af[4], bfr[4];
#pragma unroll
    for (int mi = 0; mi < 4; mi++)
      af[mi] = *reinterpret_cast<const bf16x8*>(&As[(mw + mi * 16 + lr) * 32 + lq * 8]);
#pragma unroll
    for (int ni = 0; ni < 4; ni++)
      bfr[ni] = *reinterpret_cast<const bf16x8*>(&Bs[(lq * 128 + nw + ni * 16 + lr) * 8]);
#pragma unroll
    for (int mi = 0; mi < 4; mi++)
#pragma unroll
      for (int ni = 0; ni < 4; ni++)
        acc[mi][ni] = __builtin_amdgcn_mfma_f32_16x16x32_bf16(af[mi], bfr[ni], acc[mi][ni], 0, 0, 0);
  }
#pragma unroll
  for (int mi = 0; mi < 4; mi++) {
    int m = m0 + mw + mi * 16 + lq * 4;
#pragma unroll
    for (int ni = 0; ni < 4; ni++) {
      int n = n0 + nw + ni * 16 + lr;
#pragma unroll
      for (int r = 0; r < 4; r++) {
        size_t off = (size_t)b * M * N + (size_t)(m + r) * N + n;
        if constexpr (OUT_BF16) ((ushort*)outv)[off] = f2bf(acc[mi][ni][r]);
        else                    ((float*)outv)[off] = acc[mi][ni][r];
      }
    }
  }
}

// ---------------- bf16-input MFMA GEMM (m97 structure, verified r7): GEMM2 ----------------
template<bool OUT_BF16>
__global__ __launch_bounds__(256) void k_gemm(const ushort* __restrict__ W,
                                              const ushort* __restrict__ Xt,
                                              void* __restrict__ outv,
                                              int M, int Kd, int N) {
  __shared__ __align__(16) ushort As[128 * 32];  // 8 KB, linear
  __shared__ __align__(16) ushort Bs[128 * 32];  // 8 KB, linear
  int b = blockIdx.z;
  const ushort* X = Xt + (size_t)b * N * Kd;
  int m0 = blockIdx.y * 128, n0 = blockIdx.x * 128;
  int tid = threadIdx.x;
  int w = tid >> 6, lane = tid & 63;
  int lr = lane & 15, lq = lane >> 4;
  int mw = (w >> 1) * 64, nw = (w & 1) * 64;
  int r0 = tid >> 2, c0 = tid & 3;

  ushort* dA0 = As + w * 512;
  ushort* dA1 = As + 2048 + w * 512;
  ushort* dB0 = Bs + w * 512;
  ushort* dB1 = Bs + 2048 + w * 512;
  const ushort* gA0 = W + (size_t)(m0 + r0) * Kd + c0 * 8;
  const ushort* gA1 = W + (size_t)(m0 + r0 + 64) * Kd + c0 * 8;
  const ushort* gB0 = X + (size_t)(n0 + r0) * Kd + c0 * 8;
  const ushort* gB1 = X + (size_t)(n0 + r0 + 64) * Kd + c0 * 8;

  f32x4 zero = {0.f, 0.f, 0.f, 0.f};
  f32x4 acc[4][4];
#pragma unroll
  for (int mi = 0; mi < 4; mi++)
#pragma unroll
    for (int ni = 0; ni < 4; ni++) acc[mi][ni] = zero;

  int nk = Kd / 32;
  for (int kt = 0; kt < nk; kt++) {
    int kk = kt * 32;
    __syncthreads();
    gload16(gA0 + kk, dA0);
    gload16(gA1 + kk, dA1);
    gload16(gB0 + kk, dB0);
    gload16(gB1 + kk, dB1);
    __syncthreads();
    bf16x8 af[4], bfr[4];
#pragma unroll
    for (int mi = 0; mi < 4; mi++)
      af[mi] = *reinterpret_cast<const bf16x8*>(&As[(mw + mi * 16 + lr) * 32 + lq * 8]);
#pragma unroll
    for (int ni = 0; ni < 4; ni++)
      bfr[ni] = *reinterpret_cast<const bf16x8*>(&Bs[(nw + ni * 16 + lr) * 32 + lq * 8]);
#pragma unroll
    for (int mi = 0; mi < 4; mi++)
#pragma unroll
      for (int ni = 0; ni < 4; ni++)
        acc[mi][ni] = __builtin_amdgcn_mfma_f32_16x16x32_bf16(af[mi], bfr[ni], acc[mi][ni], 0, 0, 0);
  }
#pragma unroll
  for (int mi = 0; mi < 4; mi++) {
    int m = m0 + mw + mi * 16 + lq * 4;
#pragma unroll
    for (int ni = 0; ni < 4; ni++) {
      int n = n0 + nw + ni * 16 + lr;
#pragma unroll
      for (int r = 0; r < 4; r++) {
        size_t off = (size_t)b * M * N + (size_t)(m + r) * N + n;
        if constexpr (OUT_BF16) ((ushort*)outv)[off] = f2bf(acc[mi][ni][r]);
        else                    ((float*)outv)[off] = acc[mi][ni][r];
      }
    }
  }
}

// ---------------- GN1 stats + Ysel pass: y = bf16(A)[gather] + Bq ----------------
// Per (o,g): accumulate sum/ssq AND write Ysel[o][g] = (gamma[o]>=0 ? max_k y : min_k y).
// Monotonicity of t(y)=leaky((y-mean)*rstd*ga+be) in y (rstd>0) makes
// max_k t(y_k) == t(Ysel) exactly (weakly-monotone rounded op chain).
// A-row (8KB) and idx table (16KB) staged in LDS: coalesced global reads only.
__global__ __launch_bounds__(256) void k_stats1y(const ushort* __restrict__ A,
                                                 const float* __restrict__ Bq,
                                                 const int* __restrict__ idx1,
                                                 const float* __restrict__ gam,
                                                 float* __restrict__ Ysel,
                                                 float* __restrict__ part) {
  __shared__ __align__(16) ushort Arow[GS];   // 8 KB
  __shared__ __align__(16) int ids[GD * 4];   // 16 KB
  __shared__ float rs[256], rq[256];
  int s = blockIdx.x, grp = blockIdx.y, b = blockIdx.z;
  int tid = threadIdx.x;
  for (int i = tid; i < GD; i += 256) {
    int4 v = *reinterpret_cast<const int4*>(&idx1[((size_t)b * GD + i) * 4]);
    v.x &= (GS - 1); v.y &= (GS - 1); v.z &= (GS - 1); v.w &= (GS - 1);
    *reinterpret_cast<int4*>(&ids[i * 4]) = v;
  }
  float sum = 0.f, ssq = 0.f;
  for (int oi = 0; oi < 16; oi++) {
    int o = grp * 128 + s * 16 + oi;
    const ushort* Ar = A + ((size_t)b * M1 + o) * GS;
    __syncthreads();  // prev-iter gathers done (also covers ids staging on oi=0)
#pragma unroll
    for (int i = tid * 8; i < GS; i += 2048)
      *reinterpret_cast<uint4*>(&Arow[i]) = *reinterpret_cast<const uint4*>(&Ar[i]);
    __syncthreads();
    const float* Br = Bq + ((size_t)b * M1 + o) * GD;
    float* Yr = Ysel + ((size_t)b * M1 + o) * GD;
    float sgn = gam[o];
    for (int g = tid; g < GD; g += 256) {
      int4 id = *reinterpret_cast<const int4*>(&ids[g * 4]);
      float base = Br[g];
      float y0 = bf2f(Arow[id.x]) + base;
      float y1 = bf2f(Arow[id.y]) + base;
      float y2 = bf2f(Arow[id.z]) + base;
      float y3 = bf2f(Arow[id.w]) + base;
      sum += y0 + y1 + y2 + y3;
      ssq += y0 * y0 + y1 * y1 + y2 * y2 + y3 * y3;
      float mx = fmaxf(fmaxf(y0, y1), fmaxf(y2, y3));
      float mn = fminf(fminf(y0, y1), fminf(y2, y3));
      Yr[g] = (sgn >= 0.f) ? mx : mn;
    }
  }
  rs[tid] = sum; rq[tid] = ssq;
  __syncthreads();
  for (int t = 128; t > 0; t >>= 1) {
    if (tid < t) { rs[tid] += rs[tid + t]; rq[tid] += rq[tid + t]; }
    __syncthreads();
  }
  if (tid == 0) {
    int key = ((b * 4 + grp) * 8 + s) * 2;
    part[key] = rs[0]; part[key + 1] = rq[0];
  }
}

// ---------------- GN2 stats + Ysel pass (stacked Y2 layout [b][768][1024]) ----------------
// rows 0..383 = A2 (W2a*hT), rows 384..767 = B2q (W2d*hT). 96-ch groups, 12 ch/split.
__global__ __launch_bounds__(256) void k_stats2y(const float* __restrict__ Y2,
                                                 const int* __restrict__ idx2,
                                                 const float* __restrict__ gam,
                                                 float* __restrict__ Ysel,
                                                 float* __restrict__ part) {
  __shared__ __align__(16) float Arow[GD];    // 4 KB
  __shared__ __align__(16) int ids[GD * 4];   // 16 KB
  __shared__ float rs[256], rq[256];
  int s = blockIdx.x, grp = blockIdx.y, b = blockIdx.z;
  int tid = threadIdx.x;
  for (int i = tid; i < GD; i += 256) {
    int4 v = *reinterpret_cast<const int4*>(&idx2[((size_t)b * GD + i) * 4]);
    v.x &= (GD - 1); v.y &= (GD - 1); v.z &= (GD - 1); v.w &= (GD - 1);
    *reinterpret_cast<int4*>(&ids[i * 4]) = v;
  }
  float sum = 0.f, ssq = 0.f;
  for (int oi = 0; oi < 12; oi++) {
    int o = grp * 96 + s * 12 + oi;
    const float* Ar = Y2 + ((size_t)b * ROWS2 + o) * GD;
    __syncthreads();
#pragma unroll
    for (int i = tid * 4; i < GD; i += 1024)
      *reinterpret_cast<float4*>(&Arow[i]) = *reinterpret_cast<const float4*>(&Ar[i]);
    __syncthreads();
    const float* Br = Y2 + ((size_t)b * ROWS2 + 384 + o) * GD;
    float* Yr = Ysel + ((size_t)b * M2 + o) * GD;
    float sgn = gam[o];
    for (int g = tid; g < GD; g += 256) {
      int4 id = *reinterpret_cast<const int4*>(&ids[g * 4]);
      float base = Br[g];
      float y0 = Arow[id.x] + base;
      float y1 = Arow[id.y] + base;
      float y2 = Arow[id.z] + base;
      float y3 = Arow[id.w] + base;
      sum += y0 + y1 + y2 + y3;
      ssq += y0 * y0 + y1 * y1 + y2 * y2 + y3 * y3;
      float mx = fmaxf(fmaxf(y0, y1), fmaxf(y2, y3));
      float mn = fminf(fminf(y0, y1), fminf(y2, y3));
      Yr[g] = (sgn >= 0.f) ? mx : mn;
    }
  }
  rs[tid] = sum; rq[tid] = ssq;
  __syncthreads();
  for (int t = 128; t > 0; t >>= 1) {
    if (tid < t) { rs[tid] += rs[tid + t]; rq[tid] += rq[tid + t]; }
    __syncthreads();
  }
  if (tid == 0) {
    int key = ((b * 4 + grp) * 8 + s) * 2;
    part[key] = rs[0]; part[key + 1] = rq[0];
  }
}

// ---------------- h = leaky(GN(Ysel)); statsfin inlined (identical arith order) ----------------
__global__ void k_h2(const float* __restrict__ Ysel, const float* __restrict__ part,
                     const float* __restrict__ gam, const float* __restrict__ bet,
                     ushort* __restrict__ hT) {
  __shared__ ushort tile[64][66];  // pitch 66: conflict-free column reads
  int g0 = blockIdx.x * 64, o0 = blockIdx.y * 64, b = blockIdx.z;
  int tid = threadIdx.x;
  int tkey = b * 4 + (o0 >> 7);
  float s = 0.f, q = 0.f;
#pragma unroll
  for (int i = 0; i < 8; i++) { s += part[(tkey * 8 + i) * 2]; q += part[(tkey * 8 + i) * 2 + 1]; }
  float mean = s * (1.0f / 524288.0f);
  float var = q * (1.0f / 524288.0f) - mean * mean;
  float rstd = 1.0f / sqrtf(fmaxf(var, 0.0f) + EPS_);
  int gx = tid & 63, oy = tid >> 6;
#pragma unroll
  for (int oi = 0; oi < 16; oi++) {
    int ol = oi * 4 + oy;
    int o = o0 + ol;
    float y = Ysel[((size_t)b * M1 + o) * GD + g0 + gx];
    float v = (y - mean) * rstd * gam[o] + bet[o];
    v = v >= 0.f ? v : NEG * v;
    tile[ol][gx] = f2bf(v);
  }
  __syncthreads();
  int col = tid & 63, r4 = tid >> 6;
#pragma unroll
  for (int i = 0; i < 16; i++) {
    int gl = i * 4 + r4;
    hT[((size_t)b * GD + g0 + gl) * K2C + o0 + col] = tile[col][gl];
  }
}

// ---------------- final: out = leaky(GN2(Ysel2)), statsfin inlined -> f32 ----------------
__global__ void k_out2(const float* __restrict__ Ysel2, const float* __restrict__ part,
                       const float* __restrict__ gam, const float* __restrict__ bet,
                       float* __restrict__ out) {
  int b = blockIdx.z, o = blockIdx.y;
  int g = blockIdx.x * 256 + threadIdx.x;
  int tkey = b * 4 + o / 96;
  float s = 0.f, q = 0.f;
#pragma unroll
  for (int i = 0; i < 8; i++) { s += part[(tkey * 8 + i) * 2]; q += part[(tkey * 8 + i) * 2 + 1]; }
  float mean = s * (1.0f / 393216.0f);
  float var = q * (1.0f / 393216.0f) - mean * mean;
  float rstd = 1.0f / sqrtf(fmaxf(var, 0.0f) + EPS_);
  float y = Ysel2[((size_t)b * M2 + o) * GD + g];
  float v = (y - mean) * rstd * gam[o] + bet[o];
  v = v >= 0.f ? v : NEG * v;
  out[((size_t)b * M2 + o) * GD + g] = v;
}

extern "C" void kernel_launch(void* const* d_in, const int* in_sizes, int n_in,
                              void* d_out, int out_size, void* d_ws, size_t ws_size,
                              hipStream_t stream) {
  (void)in_sizes; (void)n_in; (void)out_size;
  const float* coor  = (const float*)d_in[0];  // [16][3][4096] f32
  const float* f     = (const float*)d_in[1];  // [16][384][4096]
  const float* coorq = (const float*)d_in[2];  // [16][3][1024]
  const float* fq    = (const float*)d_in[3];  // [16][384][1024]
  const float* W1    = (const float*)d_in[4];  // [512][768]
  const float* g1    = (const float*)d_in[5];
  const float* b1    = (const float*)d_in[6];
  const float* W2    = (const float*)d_in[7];  // [384][1024]
  const float* g2    = (const float*)d_in[8];
  const float* b2    = (const float*)d_in[9];

  // Required workspace ~182.5 MB (internal buffer layout unchanged; skip cleanly if short).
  if (ws_size < 182468608u) return;

  char* ws = (char*)d_ws;
  int*    idx1 = (int*)(ws + 0);            // 256 KB
  int*    idx2 = (int*)(ws + 0x40000);      // 256 KB
  float*  s1p  = (float*)(ws + 0x80000);    // 4 KB
  float*  s2p  = (float*)(ws + 0x82000);
  ushort* W1a  = (ushort*)(ws + 0x84000);           // 512*384 bf16
  ushort* W1d  = W1a + (size_t)512 * 384;
  ushort* W2a  = W1d + (size_t)512 * 384;           // 384*512 (W2d contiguous after -> stacked M=768 GEMM)
  ushort* W2d  = W2a + (size_t)384 * 512;
  ushort* fT   = W2d + (size_t)384 * 512;           // region reused: Y2/Ysel1 aliases (fT itself now dead)
  ushort* fqT  = fT + (size_t)B_ * GS * CIN;        // dead (transpose fused into GEMM1s)
  ushort* Abuf = fqT + (size_t)B_ * GD * CIN;       // [16][512][4096] bf16, 67.1 MB
  float*  Bq   = (float*)(Abuf + (size_t)B_ * M1 * GS);   // [16][512][1024] f32, 33.6 MB
  ushort* hT   = (ushort*)((char*)Bq + (size_t)B_ * M1 * GD * 4); // [16][1024][512] bf16, 16.8 MB
  // Y2 = stacked block2 GEMM output [16][768][1024] f32 (rows 0..383 = A2, 384..767 = B2q).
  float*  Y2   = (float*)fT;
  // Ysel1 aliases the same region (consumed by k_h2 BEFORE the stacked GEMM overwrites).
  float*  Ysel1 = (float*)fT;                       // [16][512][1024] f32, 33.6 MB
  // Ysel2 aliases dead Abuf (Abuf's last reader is k_stats1y).
  float*  Ysel2 = (float*)Abuf;                     // [16][384][1024] f32, 25.2 MB
  // s2 tables live in the not-yet-written hT region (read only by k_knn, which
  // completes before k_h2 writes hT -> stream-ordered safe; no extra ws needed).
  float*  s2s  = (float*)hT;                        // [16][4096] f32, 256 KB
  float*  s2q  = s2s + (size_t)B_ * GS;             // [16][1024] f32, 64 KB

  // 1. fused prep: weight split/convert + s2 tables (one launch)
  k_prep<<<dim3(1856), 256, 0, stream>>>(W1, W2, W1a, W1d, W2a, W2d,
                                         coor, coorq, s2s, s2q);

  // 2. kNN index sets (2 queries/wave, shared candidate loads, double-buffered)
  k_knn<GS><<<dim3(GD / 8, B_), 256, 0, stream>>>(coorq, coor, s2q, s2s, idx1);
  k_knn<GD><<<dim3(GD / 8, B_), 256, 0, stream>>>(coorq, coorq, s2q, s2q, idx2);

  // 3. block1 GEMMs with fused transpose+convert (read f/fq f32 directly)
  k_gemmF<true ><<<dim3(GS / 128, M1 / 128, B_), 256, 0, stream>>>(W1a, f, Abuf, M1, CIN, GS);
  k_gemmF<false><<<dim3(GD / 128, M1 / 128, B_), 256, 0, stream>>>(W1d, fq, Bq, M1, CIN, GD);

  // 4. GN1 stats + Ysel1 (single gather pass), then streaming h transform (statsfin inline)
  k_stats1y<<<dim3(8, 4, B_), 256, 0, stream>>>(Abuf, Bq, idx1, g1, Ysel1, s1p);
  k_h2<<<dim3(GD / 64, M1 / 64, B_), 256, 0, stream>>>(Ysel1, s1p, g1, b1, hT);

  // 5. block2 GEMM, stacked: [W2a; W2d] (M=768) * hT -> Y2 (one pass over hT)
  k_gemm<false><<<dim3(GD / 128, ROWS2 / 128, B_), 256, 0, stream>>>(W2a, hT, Y2, ROWS2, K2C, GD);

  // 6. GN2 stats + Ysel2 (single gather pass), then streaming final output (statsfin inline)
  k_stats2y<<<dim3(8, 4, B_), 256, 0, stream>>>(Y2, idx2, g2, Ysel2, s2p);
  k_out2<<<dim3(GD / 256, M2, B_), 256, 0, stream>>>(Ysel2, s2p, g2, b2, (float*)d_out);
}

// Round 11
// 430.529 us; speedup vs baseline: 1.0510x; 1.0118x over previous
//
#include <hip/hip_runtime.h>
#include <stdint.h>

// Problem constants (DGCNN propagation). Inputs/outputs are FLOAT32 (per the
// reference's jnp.float32 setup_inputs); internals use bf16 MFMA (2% threshold).
#define B_   16
#define CIN  384     // C
#define GS   4096    // source points (power of 2 -> maskable)
#define GD   1024    // query points  (power of 2 -> maskable)
#define M1   512     // block1 out channels
#define K2C  512     // block2 in channels (= M1)
#define M2   384     // block2 out channels (= C)
#define ROWS2 768    // stacked block2 GEMM rows (W2a on top of W2d)
#define NEG  0.2f
#define EPS_ 1e-5f

typedef __bf16 bf16x8 __attribute__((ext_vector_type(8)));
typedef float  f32x4  __attribute__((ext_vector_type(4)));
typedef float  f32x2  __attribute__((ext_vector_type(2)));
typedef unsigned long long u64k;

__device__ __forceinline__ float bf2f(ushort u) {
  uint32_t v = ((uint32_t)u) << 16;
  return __builtin_bit_cast(float, v);
}
__device__ __forceinline__ ushort f2bf(float f) {
  uint32_t x = __builtin_bit_cast(uint32_t, f);
  x += 0x7FFFu + ((x >> 16) & 1u);
  return (ushort)(x >> 16);
}

// Packed dual-f32 ops (CDNA full-rate packed fp32). Each half is an ordinary
// IEEE f32 op -> bit-identical to scalar mul/add in the same order.
__device__ __forceinline__ f32x2 pk_mul(f32x2 a, f32x2 b) {
  f32x2 d; asm("v_pk_mul_f32 %0, %1, %2" : "=v"(d) : "v"(a), "v"(b)); return d;
}
__device__ __forceinline__ f32x2 pk_add(f32x2 a, f32x2 b) {
  f32x2 d; asm("v_pk_add_f32 %0, %1, %2" : "=v"(d) : "v"(a), "v"(b)); return d;
}
__device__ __forceinline__ f32x2 pk_fma(f32x2 a, f32x2 b, f32x2 c) {
  f32x2 d; asm("v_pk_fma_f32 %0, %1, %2, %3" : "=v"(d) : "v"(a), "v"(b), "v"(c)); return d;
}

// async global->LDS, 16B per lane. Dest must be wave-uniform base; HW adds lane*16.
__device__ __forceinline__ void gload16(const void* g, void* l) {
  __builtin_amdgcn_global_load_lds(
      (const __attribute__((address_space(1))) void*)g,
      (__attribute__((address_space(3))) void*)l, 16, 0, 0);
}

// ---------------- fused prep: weight split/convert + s2 tables (one launch) ----------------
// blocks 0..767: W1 (Kh=384); 768..1535: W2 (Kh=512); 1536..1855: s2 tables.
__global__ void k_prep(const float* __restrict__ W1, const float* __restrict__ W2,
                       ushort* __restrict__ W1a, ushort* __restrict__ W1d,
                       ushort* __restrict__ W2a, ushort* __restrict__ W2d,
                       const float* __restrict__ cs, const float* __restrict__ cqv,
                       float* __restrict__ s2s, float* __restrict__ s2q) {
#pragma clang fp contract(off)
  int blk = blockIdx.x;
  if (blk < 768) {
    int t = blk * 256 + threadIdx.x;
    int o = t / 384, c = t % 384;
    float wa = W1[(size_t)o * 768 + c];
    float wb = W1[(size_t)o * 768 + 384 + c];
    W1a[t] = f2bf(wa);
    W1d[t] = f2bf(wb - wa);
  } else if (blk < 1536) {
    int t = (blk - 768) * 256 + threadIdx.x;
    int o = t / 512, c = t % 512;
    float wa = W2[(size_t)o * 1024 + c];
    float wb = W2[(size_t)o * 1024 + 512 + c];
    W2a[t] = f2bf(wa);
    W2d[t] = f2bf(wb - wa);
  } else {
    int u = blk - 1536;                 // [0, 320): 16 batches x 20 blocks
    int b = u / 20;
    int i = (u % 20) * 256 + threadIdx.x;
    if (i < GS) {
      const float* cb = cs + (size_t)b * 3 * GS;
      float x = cb[i], y = cb[GS + i], z = cb[2 * GS + i];
      s2s[(size_t)b * GS + i] = (x * x + y * y) + z * z;
    } else {
      int j = i - GS;
      const float* cb = cqv + (size_t)b * 3 * GD;
      float x = cb[j], y = cb[GD + j], z = cb[2 * GD + j];
      s2q[(size_t)b * GD + j] = (x * x + y * y) + z * z;
    }
  }
}

// ---------------- kNN: wave-per-2-queries, u64-key sort4+bitonic-merge top-4 ----------------
// Distance values bit-identical to the verified serial version (see r1/r3 notes):
// s2 precomputed, dot via pk ops, d = pk_fma(dot,-2,q2+s2) == (q2+s2)-2*dot exactly.
// Selection: key = (monotone d bits, j) as u64 -> lex (d, idx) order == jax top_k
// tie-break (d never -0.0: q2+s2 >= 0, exact-zero fma -> +0.0 in RNE).
// Each wave processes TWO queries against the same candidate stream: the 4
// float4 loads per iteration are shared and the two independent sort/merge
// chains double ILP. Loads double-buffered (2-deep unroll, no register copies).
__device__ __forceinline__ uint32_t dmap(float d) {
  uint32_t u = __builtin_bit_cast(uint32_t, d);
  return u ^ (((uint32_t)((int32_t)u >> 31)) | 0x80000000u);  // monotone map f32 -> u32
}
__device__ __forceinline__ u64k mkkey(uint32_t hi, uint32_t lo) {
  uint2 t; t.x = lo; t.y = hi;               // register-pair build: no shift/or
  return __builtin_bit_cast(u64k, t);
}
__device__ __forceinline__ void kce(u64k& a, u64k& b) {
  bool c = b < a;
  u64k lo = c ? b : a, hi = c ? a : b;
  a = lo; b = hi;
}
__device__ __forceinline__ void klmin(u64k& a, u64k b) { a = b < a ? b : a; }

template<int GSRC>
__global__ __launch_bounds__(256) void k_knn(const float* __restrict__ cq,
                                             const float* __restrict__ ck,
                                             const float* __restrict__ s2qry,
                                             const float* __restrict__ s2src,
                                             int* __restrict__ idx) {
  constexpr int ITERS = GSRC / 256;
  static_assert(ITERS % 2 == 0, "even iteration count required for 2-deep unroll");
  int tid = threadIdx.x;
  int lane = tid & 63, wv = tid >> 6;
  int b = blockIdx.y;
  int qA = blockIdx.x * 8 + wv * 2;     // two queries per wave
  int qB = qA + 1;
  const float* cqb = cq + (size_t)b * 3 * GD;
  const float* ckb = ck + (size_t)b * 3 * GSRC;
  const float* s2b = s2src + (size_t)b * GSRC;
  float qxA = cqb[qA], qyA = cqb[GD + qA], qzA = cqb[2 * GD + qA];
  float qxB = cqb[qB], qyB = cqb[GD + qB], qzB = cqb[2 * GD + qB];
  float q2A = s2qry[(size_t)b * GD + qA];
  float q2B = s2qry[(size_t)b * GD + qB];
  f32x2 qxpA = {qxA, qxA}, qypA = {qyA, qyA}, qzpA = {qzA, qzA}, q2pA = {q2A, q2A};
  f32x2 qxpB = {qxB, qxB}, qypB = {qyB, qyB}, qzpB = {qzB, qzB}, q2pB = {q2B, q2B};
  f32x2 m2p = {-2.f, -2.f};

  u64k kA0 = ~0ull, kA1 = ~0ull, kA2 = ~0ull, kA3 = ~0ull;  // sorted-4 asc (query A)
  u64k kB0 = ~0ull, kB1 = ~0ull, kB2 = ~0ull, kB3 = ~0ull;  // sorted-4 asc (query B)

#define KNN_Q(QXP, QYP, QZP, Q2P, K0, K1, K2, K3)                              \
  {                                                                            \
    f32x2 dotl = pk_add(pk_add(pk_mul(QXP, xl), pk_mul(QYP, yl)), pk_mul(QZP, zl)); \
    f32x2 doth = pk_add(pk_add(pk_mul(QXP, xh), pk_mul(QYP, yh)), pk_mul(QZP, zh)); \
    f32x2 dl = pk_fma(dotl, m2p, pk_add(Q2P, sl));                             \
    f32x2 dh = pk_fma(doth, m2p, pk_add(Q2P, sh));                             \
    u64k n0 = mkkey(dmap(dl.x), j0u);                                          \
    u64k n1 = mkkey(dmap(dl.y), j0u + 1);                                      \
    u64k n2 = mkkey(dmap(dh.x), j0u + 2);                                      \
    u64k n3 = mkkey(dmap(dh.y), j0u + 3);                                      \
    kce(n0, n1); kce(n2, n3); kce(n0, n2); kce(n1, n3); kce(n1, n2);           \
    klmin(K0, n3); klmin(K1, n2); klmin(K2, n1); klmin(K3, n0);                \
    kce(K0, K2); kce(K1, K3); kce(K0, K1); kce(K2, K3);                        \
  }

#define KNN_STEP(Xv, Yv, Zv, Sv, J0)                                           \
  {                                                                            \
    f32x2 xl = {Xv.x, Xv.y}, xh = {Xv.z, Xv.w};                                \
    f32x2 yl = {Yv.x, Yv.y}, yh = {Yv.z, Yv.w};                                \
    f32x2 zl = {Zv.x, Zv.y}, zh = {Zv.z, Zv.w};                                \
    f32x2 sl = {Sv.x, Sv.y}, sh = {Sv.z, Sv.w};                                \
    uint32_t j0u = (uint32_t)(J0);                                             \
    KNN_Q(qxpA, qypA, qzpA, q2pA, kA0, kA1, kA2, kA3);                         \
    KNN_Q(qxpB, qypB, qzpB, q2pB, kB0, kB1, kB2, kB3);                         \
  }

#define KNN_LOAD(Xv, Yv, Zv, Sv, J)                                            \
  {                                                                            \
    Xv = *reinterpret_cast<const float4*>(ckb + (J));                          \
    Yv = *reinterpret_cast<const float4*>(ckb + GSRC + (J));                   \
    Zv = *reinterpret_cast<const float4*>(ckb + 2 * GSRC + (J));               \
    Sv = *reinterpret_cast<const float4*>(s2b + (J));                          \
  }

  int base = lane * 4;
  float4 X0, Y0, Z0, S0, X1, Y1, Z1, S1;
  KNN_LOAD(X0, Y0, Z0, S0, base);
  for (int it = 0; it < ITERS; it += 2) {
    int j0 = it * 256 + base;
    KNN_LOAD(X1, Y1, Z1, S1, j0 + 256);           // prefetch it+1 (always valid)
    KNN_STEP(X0, Y0, Z0, S0, j0);
    if (it + 2 < ITERS) KNN_LOAD(X0, Y0, Z0, S0, j0 + 512);  // prefetch it+2
    KNN_STEP(X1, Y1, Z1, S1, j0 + 256);
  }
#undef KNN_STEP
#undef KNN_Q
#undef KNN_LOAD

  // 6-step butterfly: merge two sorted 4-lists -> lowest 4 (bitonic, lex order),
  // run independently for both queries.
#pragma unroll
  for (int off = 1; off < 64; off <<= 1) {
    u64k p0 = __shfl_xor(kA0, off), p1 = __shfl_xor(kA1, off);
    u64k p2 = __shfl_xor(kA2, off), p3 = __shfl_xor(kA3, off);
    klmin(kA0, p3); klmin(kA1, p2); klmin(kA2, p1); klmin(kA3, p0);
    kce(kA0, kA2); kce(kA1, kA3); kce(kA0, kA1); kce(kA2, kA3);
    u64k r0 = __shfl_xor(kB0, off), r1 = __shfl_xor(kB1, off);
    u64k r2 = __shfl_xor(kB2, off), r3 = __shfl_xor(kB3, off);
    klmin(kB0, r3); klmin(kB1, r2); klmin(kB2, r1); klmin(kB3, r0);
    kce(kB0, kB2); kce(kB1, kB3); kce(kB0, kB1); kce(kB2, kB3);
  }
  if (lane == 0) {
    int4 ra;
    ra.x = (int)(uint32_t)kA0; ra.y = (int)(uint32_t)kA1;
    ra.z = (int)(uint32_t)kA2; ra.w = (int)(uint32_t)kA3;
    *reinterpret_cast<int4*>(&idx[((size_t)b * GD + qA) * 4]) = ra;
    int4 rb;
    rb.x = (int)(uint32_t)kB0; rb.y = (int)(uint32_t)kB1;
    rb.z = (int)(uint32_t)kB2; rb.w = (int)(uint32_t)kB3;
    *reinterpret_cast<int4*>(&idx[((size_t)b * GD + qB) * 4]) = rb;
  }
}

// ---------------- fused transpose+convert GEMM with async-STAGE split (T14) ----------------
// out[b] = W(MxK) * bf16(X32[b](KxN)). B-path: iteration kt+1's 16 f32 loads are
// ISSUED right after the second barrier (can't hoist above __syncthreads), so
// their latency hides under the ds_read+MFMA phase; the stage phase only
// converts+stores already-landed registers. Conflict-free Bs [4][128][8]
// (consecutive lanes -> consecutive 16B chunks, r10-verified). A-side: gload16
// linear (r7-verified). Values bit-identical (same f2bf per element, same order).
template<bool OUT_BF16>
__global__ __launch_bounds__(256) void k_gemmF(const ushort* __restrict__ W,
                                               const float* __restrict__ X32,
                                               void* __restrict__ outv,
                                               int M, int Kd, int N) {
  __shared__ __align__(16) ushort As[128 * 32];   // 8 KB, linear (gload16 dest)
  __shared__ __align__(16) ushort Bs[4 * 128 * 8]; // 8 KB, [g][n][8] chunks
  int b = blockIdx.z;
  const float* X = X32 + (size_t)b * Kd * N;
  int m0 = blockIdx.y * 128, n0 = blockIdx.x * 128;
  int tid = threadIdx.x;
  int w = tid >> 6, lane = tid & 63;
  int lr = lane & 15, lq = lane >> 4;
  int mw = (w >> 1) * 64, nw = (w & 1) * 64;
  int r0 = tid >> 2, c0 = tid & 3;

  ushort* dA0 = As + w * 512;
  ushort* dA1 = As + 2048 + w * 512;
  const ushort* gA0 = W + (size_t)(m0 + r0) * Kd + c0 * 8;
  const ushort* gA1 = W + (size_t)(m0 + r0 + 64) * Kd + c0 * 8;

  int bn = tid & 127;          // n within tile (B staging)
  int bg = tid >> 7;           // k-group base 0/1 (handles bg and bg+2)
  const float* Xcol = X + n0 + bn;

  float pb[16];                // B prefetch registers (all indices compile-time)

#define LOADB(KK)                                                              \
  {                                                                            \
    _Pragma("unroll")                                                          \
    for (int gg = 0; gg < 2; gg++) {                                           \
      const float* Xg = Xcol + (size_t)((KK) + (bg + gg * 2) * 8) * N;         \
      _Pragma("unroll")                                                        \
      for (int j = 0; j < 8; j++) pb[gg * 8 + j] = Xg[(size_t)j * N];          \
    }                                                                          \
  }
#define STOREB()                                                               \
  {                                                                            \
    _Pragma("unroll")                                                          \
    for (int gg = 0; gg < 2; gg++) {                                           \
      uint4 pkv;                                                               \
      pkv.x = (uint32_t)f2bf(pb[gg * 8 + 0]) | ((uint32_t)f2bf(pb[gg * 8 + 1]) << 16); \
      pkv.y = (uint32_t)f2bf(pb[gg * 8 + 2]) | ((uint32_t)f2bf(pb[gg * 8 + 3]) << 16); \
      pkv.z = (uint32_t)f2bf(pb[gg * 8 + 4]) | ((uint32_t)f2bf(pb[gg * 8 + 5]) << 16); \
      pkv.w = (uint32_t)f2bf(pb[gg * 8 + 6]) | ((uint32_t)f2bf(pb[gg * 8 + 7]) << 16); \
      *reinterpret_cast<uint4*>(&Bs[((bg + gg * 2) * 128 + bn) * 8]) = pkv;    \
    }                                                                          \
  }

  f32x4 zero = {0.f, 0.f, 0.f, 0.f};
  f32x4 acc[4][4];
#pragma unroll
  for (int mi = 0; mi < 4; mi++)
#pragma unroll
    for (int ni = 0; ni < 4; ni++) acc[mi][ni] = zero;

  int nk = Kd / 32;
  LOADB(0);                             // prologue prefetch
  for (int kt = 0; kt < nk; kt++) {
    int kk = kt * 32;
    __syncthreads();                    // prev-iter LDS reads done
    gload16(gA0 + kk, dA0);
    gload16(gA1 + kk, dA1);
    STOREB();                           // convert+store regs (loads landed long ago)
    __syncthreads();                    // drains gloadA; Bs visible
    if (kt + 1 < nk) LOADB(kk + 32);    // issue next-iter loads AFTER the barrier:
                                        // latency hides under ds_read+MFMA below
    bf16x8 af[4], bfr[4];
#pragma unroll
    for (int mi = 0; mi < 4; mi++)
      af[mi] = *reinterpret_cast<const bf16x8*>(&As[(mw + mi * 16 + lr) * 32 + lq * 8]);
#pragma unroll
    for (int ni = 0; ni < 4; ni++)
      bfr[ni] = *reinterpret_cast<const bf16x8*>(&Bs[(lq * 128 + nw + ni * 16 + lr) * 8]);
#pragma unroll
    for (int mi = 0; mi < 4; mi++)
#pragma unroll
      for (int ni = 0; ni < 4; ni++)
        acc[mi][ni] = __builtin_amdgcn_mfma_f32_16x16x32_bf16(af[mi], bfr[ni], acc[mi][ni], 0, 0, 0);
  }
#undef LOADB
#undef STOREB
#pragma unroll
  for (int mi = 0; mi < 4; mi++) {
    int m = m0 + mw + mi * 16 + lq * 4;
#pragma unroll
    for (int ni = 0; ni < 4; ni++) {
      int n = n0 + nw + ni * 16 + lr;
#pragma unroll
      for (int r = 0; r < 4; r++) {
        size_t off = (size_t)b * M * N + (size_t)(m + r) * N + n;
        if constexpr (OUT_BF16) ((ushort*)outv)[off] = f2bf(acc[mi][ni][r]);
        else                    ((float*)outv)[off] = acc[mi][ni][r];
      }
    }
  }
}

// ---------------- bf16-input MFMA GEMM (m97 structure, verified r7): GEMM2 ----------------
template<bool OUT_BF16>
__global__ __launch_bounds__(256) void k_gemm(const ushort* __restrict__ W,
                                              const ushort* __restrict__ Xt,
                                              void* __restrict__ outv,
                                              int M, int Kd, int N) {
  __shared__ __align__(16) ushort As[128 * 32];  // 8 KB, linear
  __shared__ __align__(16) ushort Bs[128 * 32];  // 8 KB, linear
  int b = blockIdx.z;
  const ushort* X = Xt + (size_t)b * N * Kd;
  int m0 = blockIdx.y * 128, n0 = blockIdx.x * 128;
  int tid = threadIdx.x;
  int w = tid >> 6, lane = tid & 63;
  int lr = lane & 15, lq = lane >> 4;
  int mw = (w >> 1) * 64, nw = (w & 1) * 64;
  int r0 = tid >> 2, c0 = tid & 3;

  ushort* dA0 = As + w * 512;
  ushort* dA1 = As + 2048 + w * 512;
  ushort* dB0 = Bs + w * 512;
  ushort* dB1 = Bs + 2048 + w * 512;
  const ushort* gA0 = W + (size_t)(m0 + r0) * Kd + c0 * 8;
  const ushort* gA1 = W + (size_t)(m0 + r0 + 64) * Kd + c0 * 8;
  const ushort* gB0 = X + (size_t)(n0 + r0) * Kd + c0 * 8;
  const ushort* gB1 = X + (size_t)(n0 + r0 + 64) * Kd + c0 * 8;

  f32x4 zero = {0.f, 0.f, 0.f, 0.f};
  f32x4 acc[4][4];
#pragma unroll
  for (int mi = 0; mi < 4; mi++)
#pragma unroll
    for (int ni = 0; ni < 4; ni++) acc[mi][ni] = zero;

  int nk = Kd / 32;
  for (int kt = 0; kt < nk; kt++) {
    int kk = kt * 32;
    __syncthreads();
    gload16(gA0 + kk, dA0);
    gload16(gA1 + kk, dA1);
    gload16(gB0 + kk, dB0);
    gload16(gB1 + kk, dB1);
    __syncthreads();
    bf16x8 af[4], bfr[4];
#pragma unroll
    for (int mi = 0; mi < 4; mi++)
      af[mi] = *reinterpret_cast<const bf16x8*>(&As[(mw + mi * 16 + lr) * 32 + lq * 8]);
#pragma unroll
    for (int ni = 0; ni < 4; ni++)
      bfr[ni] = *reinterpret_cast<const bf16x8*>(&Bs[(nw + ni * 16 + lr) * 32 + lq * 8]);
#pragma unroll
    for (int mi = 0; mi < 4; mi++)
#pragma unroll
      for (int ni = 0; ni < 4; ni++)
        acc[mi][ni] = __builtin_amdgcn_mfma_f32_16x16x32_bf16(af[mi], bfr[ni], acc[mi][ni], 0, 0, 0);
  }
#pragma unroll
  for (int mi = 0; mi < 4; mi++) {
    int m = m0 + mw + mi * 16 + lq * 4;
#pragma unroll
    for (int ni = 0; ni < 4; ni++) {
      int n = n0 + nw + ni * 16 + lr;
#pragma unroll
      for (int r = 0; r < 4; r++) {
        size_t off = (size_t)b * M * N + (size_t)(m + r) * N + n;
        if constexpr (OUT_BF16) ((ushort*)outv)[off] = f2bf(acc[mi][ni][r]);
        else                    ((float*)outv)[off] = acc[mi][ni][r];
      }
    }
  }
}

// ---------------- GN1 stats + Ysel pass: y = bf16(A)[gather] + Bq ----------------
// Per (o,g): accumulate sum/ssq AND write Ysel[o][g] = (gamma[o]>=0 ? max_k y : min_k y).
// Monotonicity of t(y)=leaky((y-mean)*rstd*ga+be) in y (rstd>0) makes
// max_k t(y_k) == t(Ysel) exactly (weakly-monotone rounded op chain).
// A-row (8KB) and idx table (16KB) staged in LDS: coalesced global reads only.
__global__ __launch_bounds__(256) void k_stats1y(const ushort* __restrict__ A,
                                                 const float* __restrict__ Bq,
                                                 const int* __restrict__ idx1,
                                                 const float* __restrict__ gam,
                                                 float* __restrict__ Ysel,
                                                 float* __restrict__ part) {
  __shared__ __align__(16) ushort Arow[GS];   // 8 KB
  __shared__ __align__(16) int ids[GD * 4];   // 16 KB
  __shared__ float rs[256], rq[256];
  int s = blockIdx.x, grp = blockIdx.y, b = blockIdx.z;
  int tid = threadIdx.x;
  for (int i = tid; i < GD; i += 256) {
    int4 v = *reinterpret_cast<const int4*>(&idx1[((size_t)b * GD + i) * 4]);
    v.x &= (GS - 1); v.y &= (GS - 1); v.z &= (GS - 1); v.w &= (GS - 1);
    *reinterpret_cast<int4*>(&ids[i * 4]) = v;
  }
  float sum = 0.f, ssq = 0.f;
  for (int oi = 0; oi < 16; oi++) {
    int o = grp * 128 + s * 16 + oi;
    const ushort* Ar = A + ((size_t)b * M1 + o) * GS;
    __syncthreads();  // prev-iter gathers done (also covers ids staging on oi=0)
#pragma unroll
    for (int i = tid * 8; i < GS; i += 2048)
      *reinterpret_cast<uint4*>(&Arow[i]) = *reinterpret_cast<const uint4*>(&Ar[i]);
    __syncthreads();
    const float* Br = Bq + ((size_t)b * M1 + o) * GD;
    float* Yr = Ysel + ((size_t)b * M1 + o) * GD;
    float sgn = gam[o];
    for (int g = tid; g < GD; g += 256) {
      int4 id = *reinterpret_cast<const int4*>(&ids[g * 4]);
      float base = Br[g];
      float y0 = bf2f(Arow[id.x]) + base;
      float y1 = bf2f(Arow[id.y]) + base;
      float y2 = bf2f(Arow[id.z]) + base;
      float y3 = bf2f(Arow[id.w]) + base;
      sum += y0 + y1 + y2 + y3;
      ssq += y0 * y0 + y1 * y1 + y2 * y2 + y3 * y3;
      float mx = fmaxf(fmaxf(y0, y1), fmaxf(y2, y3));
      float mn = fminf(fminf(y0, y1), fminf(y2, y3));
      Yr[g] = (sgn >= 0.f) ? mx : mn;
    }
  }
  rs[tid] = sum; rq[tid] = ssq;
  __syncthreads();
  for (int t = 128; t > 0; t >>= 1) {
    if (tid < t) { rs[tid] += rs[tid + t]; rq[tid] += rq[tid + t]; }
    __syncthreads();
  }
  if (tid == 0) {
    int key = ((b * 4 + grp) * 8 + s) * 2;
    part[key] = rs[0]; part[key + 1] = rq[0];
  }
}

// ---------------- GN2 stats + Ysel pass (stacked Y2 layout [b][768][1024]) ----------------
// rows 0..383 = A2 (W2a*hT), rows 384..767 = B2q (W2d*hT). 96-ch groups, 12 ch/split.
__global__ __launch_bounds__(256) void k_stats2y(const float* __restrict__ Y2,
                                                 const int* __restrict__ idx2,
                                                 const float* __restrict__ gam,
                                                 float* __restrict__ Ysel,
                                                 float* __restrict__ part) {
  __shared__ __align__(16) float Arow[GD];    // 4 KB
  __shared__ __align__(16) int ids[GD * 4];   // 16 KB
  __shared__ float rs[256], rq[256];
  int s = blockIdx.x, grp = blockIdx.y, b = blockIdx.z;
  int tid = threadIdx.x;
  for (int i = tid; i < GD; i += 256) {
    int4 v = *reinterpret_cast<const int4*>(&idx2[((size_t)b * GD + i) * 4]);
    v.x &= (GD - 1); v.y &= (GD - 1); v.z &= (GD - 1); v.w &= (GD - 1);
    *reinterpret_cast<int4*>(&ids[i * 4]) = v;
  }
  float sum = 0.f, ssq = 0.f;
  for (int oi = 0; oi < 12; oi++) {
    int o = grp * 96 + s * 12 + oi;
    const float* Ar = Y2 + ((size_t)b * ROWS2 + o) * GD;
    __syncthreads();
#pragma unroll
    for (int i = tid * 4; i < GD; i += 1024)
      *reinterpret_cast<float4*>(&Arow[i]) = *reinterpret_cast<const float4*>(&Ar[i]);
    __syncthreads();
    const float* Br = Y2 + ((size_t)b * ROWS2 + 384 + o) * GD;
    float* Yr = Ysel + ((size_t)b * M2 + o) * GD;
    float sgn = gam[o];
    for (int g = tid; g < GD; g += 256) {
      int4 id = *reinterpret_cast<const int4*>(&ids[g * 4]);
      float base = Br[g];
      float y0 = Arow[id.x] + base;
      float y1 = Arow[id.y] + base;
      float y2 = Arow[id.z] + base;
      float y3 = Arow[id.w] + base;
      sum += y0 + y1 + y2 + y3;
      ssq += y0 * y0 + y1 * y1 + y2 * y2 + y3 * y3;
      float mx = fmaxf(fmaxf(y0, y1), fmaxf(y2, y3));
      float mn = fminf(fminf(y0, y1), fminf(y2, y3));
      Yr[g] = (sgn >= 0.f) ? mx : mn;
    }
  }
  rs[tid] = sum; rq[tid] = ssq;
  __syncthreads();
  for (int t = 128; t > 0; t >>= 1) {
    if (tid < t) { rs[tid] += rs[tid + t]; rq[tid] += rq[tid + t]; }
    __syncthreads();
  }
  if (tid == 0) {
    int key = ((b * 4 + grp) * 8 + s) * 2;
    part[key] = rs[0]; part[key + 1] = rq[0];
  }
}

// ---------------- h = leaky(GN(Ysel)); statsfin inlined (identical arith order) ----------------
__global__ void k_h2(const float* __restrict__ Ysel, const float* __restrict__ part,
                     const float* __restrict__ gam, const float* __restrict__ bet,
                     ushort* __restrict__ hT) {
  __shared__ ushort tile[64][66];  // pitch 66: conflict-free column reads
  int g0 = blockIdx.x * 64, o0 = blockIdx.y * 64, b = blockIdx.z;
  int tid = threadIdx.x;
  int tkey = b * 4 + (o0 >> 7);
  float s = 0.f, q = 0.f;
#pragma unroll
  for (int i = 0; i < 8; i++) { s += part[(tkey * 8 + i) * 2]; q += part[(tkey * 8 + i) * 2 + 1]; }
  float mean = s * (1.0f / 524288.0f);
  float var = q * (1.0f / 524288.0f) - mean * mean;
  float rstd = 1.0f / sqrtf(fmaxf(var, 0.0f) + EPS_);
  int gx = tid & 63, oy = tid >> 6;
#pragma unroll
  for (int oi = 0; oi < 16; oi++) {
    int ol = oi * 4 + oy;
    int o = o0 + ol;
    float y = Ysel[((size_t)b * M1 + o) * GD + g0 + gx];
    float v = (y - mean) * rstd * gam[o] + bet[o];
    v = v >= 0.f ? v : NEG * v;
    tile[ol][gx] = f2bf(v);
  }
  __syncthreads();
  int col = tid & 63, r4 = tid >> 6;
#pragma unroll
  for (int i = 0; i < 16; i++) {
    int gl = i * 4 + r4;
    hT[((size_t)b * GD + g0 + gl) * K2C + o0 + col] = tile[col][gl];
  }
}

// ---------------- final: out = leaky(GN2(Ysel2)), statsfin inlined -> f32 ----------------
__global__ void k_out2(const float* __restrict__ Ysel2, const float* __restrict__ part,
                       const float* __restrict__ gam, const float* __restrict__ bet,
                       float* __restrict__ out) {
  int b = blockIdx.z, o = blockIdx.y;
  int g = blockIdx.x * 256 + threadIdx.x;
  int tkey = b * 4 + o / 96;
  float s = 0.f, q = 0.f;
#pragma unroll
  for (int i = 0; i < 8; i++) { s += part[(tkey * 8 + i) * 2]; q += part[(tkey * 8 + i) * 2 + 1]; }
  float mean = s * (1.0f / 393216.0f);
  float var = q * (1.0f / 393216.0f) - mean * mean;
  float rstd = 1.0f / sqrtf(fmaxf(var, 0.0f) + EPS_);
  float y = Ysel2[((size_t)b * M2 + o) * GD + g];
  float v = (y - mean) * rstd * gam[o] + bet[o];
  v = v >= 0.f ? v : NEG * v;
  out[((size_t)b * M2 + o) * GD + g] = v;
}

extern "C" void kernel_launch(void* const* d_in, const int* in_sizes, int n_in,
                              void* d_out, int out_size, void* d_ws, size_t ws_size,
                              hipStream_t stream) {
  (void)in_sizes; (void)n_in; (void)out_size;
  const float* coor  = (const float*)d_in[0];  // [16][3][4096] f32
  const float* f     = (const float*)d_in[1];  // [16][384][4096]
  const float* coorq = (const float*)d_in[2];  // [16][3][1024]
  const float* fq    = (const float*)d_in[3];  // [16][384][1024]
  const float* W1    = (const float*)d_in[4];  // [512][768]
  const float* g1    = (const float*)d_in[5];
  const float* b1    = (const float*)d_in[6];
  const float* W2    = (const float*)d_in[7];  // [384][1024]
  const float* g2    = (const float*)d_in[8];
  const float* b2    = (const float*)d_in[9];

  // Required workspace ~182.5 MB (internal buffer layout unchanged; skip cleanly if short).
  if (ws_size < 182468608u) return;

  char* ws = (char*)d_ws;
  int*    idx1 = (int*)(ws + 0);            // 256 KB
  int*    idx2 = (int*)(ws + 0x40000);      // 256 KB
  float*  s1p  = (float*)(ws + 0x80000);    // 4 KB
  float*  s2p  = (float*)(ws + 0x82000);
  ushort* W1a  = (ushort*)(ws + 0x84000);           // 512*384 bf16
  ushort* W1d  = W1a + (size_t)512 * 384;
  ushort* W2a  = W1d + (size_t)512 * 384;           // 384*512 (W2d contiguous after -> stacked M=768 GEMM)
  ushort* W2d  = W2a + (size_t)384 * 512;
  ushort* fT   = W2d + (size_t)384 * 512;           // region reused: Y2/Ysel1 aliases (fT itself now dead)
  ushort* fqT  = fT + (size_t)B_ * GS * CIN;        // dead (transpose fused into GEMM1s)
  ushort* Abuf = fqT + (size_t)B_ * GD * CIN;       // [16][512][4096] bf16, 67.1 MB
  float*  Bq   = (float*)(Abuf + (size_t)B_ * M1 * GS);   // [16][512][1024] f32, 33.6 MB
  ushort* hT   = (ushort*)((char*)Bq + (size_t)B_ * M1 * GD * 4); // [16][1024][512] bf16, 16.8 MB
  // Y2 = stacked block2 GEMM output [16][768][1024] f32 (rows 0..383 = A2, 384..767 = B2q).
  float*  Y2   = (float*)fT;
  // Ysel1 aliases the same region (consumed by k_h2 BEFORE the stacked GEMM overwrites).
  float*  Ysel1 = (float*)fT;                       // [16][512][1024] f32, 33.6 MB
  // Ysel2 aliases dead Abuf (Abuf's last reader is k_stats1y).
  float*  Ysel2 = (float*)Abuf;                     // [16][384][1024] f32, 25.2 MB
  // s2 tables live in the not-yet-written hT region (read only by k_knn, which
  // completes before k_h2 writes hT -> stream-ordered safe; no extra ws needed).
  float*  s2s  = (float*)hT;                        // [16][4096] f32, 256 KB
  float*  s2q  = s2s + (size_t)B_ * GS;             // [16][1024] f32, 64 KB

  // 1. fused prep: weight split/convert + s2 tables (one launch)
  k_prep<<<dim3(1856), 256, 0, stream>>>(W1, W2, W1a, W1d, W2a, W2d,
                                         coor, coorq, s2s, s2q);

  // 2. kNN index sets (2 queries/wave, shared candidate loads, double-buffered)
  k_knn<GS><<<dim3(GD / 8, B_), 256, 0, stream>>>(coorq, coor, s2q, s2s, idx1);
  k_knn<GD><<<dim3(GD / 8, B_), 256, 0, stream>>>(coorq, coorq, s2q, s2q, idx2);

  // 3. block1 GEMMs with fused transpose+convert (read f/fq f32 directly, T14 prefetch)
  k_gemmF<true ><<<dim3(GS / 128, M1 / 128, B_), 256, 0, stream>>>(W1a, f, Abuf, M1, CIN, GS);
  k_gemmF<false><<<dim3(GD / 128, M1 / 128, B_), 256, 0, stream>>>(W1d, fq, Bq, M1, CIN, GD);

  // 4. GN1 stats + Ysel1 (single gather pass), then streaming h transform (statsfin inline)
  k_stats1y<<<dim3(8, 4, B_), 256, 0, stream>>>(Abuf, Bq, idx1, g1, Ysel1, s1p);
  k_h2<<<dim3(GD / 64, M1 / 64, B_), 256, 0, stream>>>(Ysel1, s1p, g1, b1, hT);

  // 5. block2 GEMM, stacked: [W2a; W2d] (M=768) * hT -> Y2 (one pass over hT)
  k_gemm<false><<<dim3(GD / 128, ROWS2 / 128, B_), 256, 0, stream>>>(W2a, hT, Y2, ROWS2, K2C, GD);

  // 6. GN2 stats + Ysel2 (single gather pass), then streaming final output (statsfin inline)
  k_stats2y<<<dim3(8, 4, B_), 256, 0, stream>>>(Y2, idx2, g2, Ysel2, s2p);
  k_out2<<<dim3(GD / 256, M2, B_), 256, 0, stream>>>(Ysel2, s2p, g2, b2, (float*)d_out);
}